// Round 6
// baseline (21139.798 us; speedup 1.0000x reference)
//
#include <hip/hip_runtime.h>
#include <math.h>

// ===== jax threefry mode: 1 = partitionable (jax >= 0.4.36 default) =====
#define JAX_PARTITIONABLE 1

// ---- model dims: NL=6 D=256 FF=1024 V=1024 S=48 BS=64 H=8 DH=32 ----

// ---- workspace layout (float offsets) ----
static constexpr int SWQKVT  = 0;                        // 6 x [256 k][768 o]
static constexpr int SWOT    = SWQKVT + 6*256*768;       // 1,179,648 ; 6 x [256][256]
static constexpr int CWQT    = SWOT   + 6*256*256;       // 1,572,864
static constexpr int CWOT    = CWQT   + 6*256*256;       // 1,966,080
static constexpr int DW1T    = CWOT   + 6*256*256;       // 2,359,296 ; 6 x [256][1024]
static constexpr int DW2T    = DW1T   + 6*256*1024;      // 3,932,160 ; 6 x [1024][256]
static constexpr int WT_END  = DW2T   + 6*1024*256;      // 5,505,024
static constexpr int CKT_OFF = WT_END;                   // 6 x 64 x [64 d4][48 p][4 c]
static constexpr int CV_OFF  = CKT_OFF + 6*64*48*256;    // 10,223,616 ; [l][b*48+p][256]
static constexpr int SKT_OFF = CV_OFF  + 6*64*48*256;    // 14,942,208
static constexpr int SV_OFF  = SKT_OFF + 6*64*48*256;    // 19,660,800
static constexpr int WS_END  = SV_OFF  + 6*64*48*256;    // 24,379,392 floats = 97.5 MB
// encoder-time aliases (dead before the regions' real use):
static constexpr int X_OFF    = 0;
static constexpr int MEM_OFF  = X_OFF + 3072*256;
static constexpr int QKV_OFF  = SKT_OFF;
static constexpr int AO_OFF   = QKV_OFF + 3072*768;
static constexpr int RES1_OFF = AO_OFF + 3072*256;
static constexpr int X1_OFF   = RES1_OFF + 3072*256;
static constexpr int HB_OFF   = SV_OFF;
static constexpr int RES2_OFF = HB_OFF + 3072*1024;
static constexpr int PCK_OFF  = SKT_OFF;
// ---- cohort soft-sync slots (relaxed-only, performance rendezvous) ----
static constexpr int SSYNC_OFF = WS_END;                 // 3072 uints (12 KB)

struct GParams {
  const int   *xc, *xct;
  const float *sos, *emb, *hw, *hb;
  const float *ewqkv, *ebqkv, *ewo, *ebo, *ew1, *eb1, *ew2, *eb2, *elnw, *elnb;
  const float *swqkv, *sbqkv, *swo, *sbo;
  const float *cwqkv, *cbqkv, *cwo, *cbo;
  const float *dw1, *db1, *dw2, *db2, *dlnw, *dlnb, *lnfw, *lnfb;
  float *out;
  float *ws;
};

// ---- device-global barrier state (generation counters survive graph replays) ----
__device__ unsigned g_cntA = 0, g_genA = 0;

static __device__ __forceinline__ void gbar(unsigned* cnt, unsigned* gen, unsigned nb) {
  __syncthreads();
  if (threadIdx.x == 0) {
    __threadfence();
    unsigned g = __hip_atomic_load(gen, __ATOMIC_RELAXED, __HIP_MEMORY_SCOPE_AGENT);
    unsigned prev = __hip_atomic_fetch_add(cnt, 1u, __ATOMIC_ACQ_REL, __HIP_MEMORY_SCOPE_AGENT);
    if (prev == nb - 1u) {
      __hip_atomic_store(cnt, 0u, __ATOMIC_RELAXED, __HIP_MEMORY_SCOPE_AGENT);
      __threadfence();
      __hip_atomic_store(gen, g + 1u, __ATOMIC_RELEASE, __HIP_MEMORY_SCOPE_AGENT);
    } else {
      while (__hip_atomic_load(gen, __ATOMIC_ACQUIRE, __HIP_MEMORY_SCOPE_AGENT) == g)
        __builtin_amdgcn_s_sleep(1);
      __threadfence();
    }
  }
  __syncthreads();
}

// ---- cohort soft-sync: relaxed-only (NO fences, NO cache invalidation).
static __device__ __forceinline__ void cohort_sync(unsigned* slot) {
  __syncthreads();
  if (threadIdx.x == 0) {
    __hip_atomic_fetch_add(slot, 1u, __ATOMIC_RELAXED, __HIP_MEMORY_SCOPE_AGENT);
    for (int it = 0; it < 64; ++it) {
      if (__hip_atomic_load(slot, __ATOMIC_RELAXED, __HIP_MEMORY_SCOPE_AGENT) >= 8u) break;
      __builtin_amdgcn_s_sleep(1);
    }
  }
  __syncthreads();
}

// ---- cooperative L2 prefetch: read 1 float per 128B line, keep via asm ----
// staggered: this WG covers lines ≡ q (mod 8) -> the 8 cohort WGs on one XCD
// together fetch the region ONCE from LLC into their shared L2.
static __device__ __forceinline__ unsigned pf_slice(const float* base, int nfloats, int q,
                                                    int tid, int nthr) {
  const unsigned* p = (const unsigned*)base;
  const int lines = nfloats >> 5;
  unsigned acc = 0;
  for (int j = q + (tid << 3); j < lines; j += (nthr << 3))
    acc ^= p[(size_t)j << 5];
  return acc;
}
static __device__ __forceinline__ unsigned pf_full(const float* base, int nfloats,
                                                   int tid, int nthr) {
  const unsigned* p = (const unsigned*)base;
  const int lines = nfloats >> 5;
  unsigned acc = 0;
  for (int j = tid; j < lines; j += nthr)
    acc ^= p[(size_t)j << 5];
  return acc;
}

struct PF {
  const float* r0; int n0;   // staggered regions (shared weights)
  const float* r1; int n1;
  const float* r2; int n2;
  const float* rp; int np;   // full regions (private KV)
  const float* rp2; int np2;
  int q;
};

static __device__ __forceinline__ void do_pf(const PF* pf, int tid, int nthr) {
  unsigned acc = 0;
  if (pf->r0)  acc ^= pf_slice(pf->r0,  pf->n0,  pf->q, tid, nthr);
  if (pf->r1)  acc ^= pf_slice(pf->r1,  pf->n1,  pf->q, tid, nthr);
  if (pf->r2)  acc ^= pf_slice(pf->r2,  pf->n2,  pf->q, tid, nthr);
  if (pf->rp)  acc ^= pf_full (pf->rp,  pf->np,  tid, nthr);
  if (pf->rp2) acc ^= pf_full (pf->rp2, pf->np2, tid, nthr);
  asm volatile("" :: "v"(acc));
}

// ---- threefry2x32 (exact jax rotation/key schedule) ----
static __device__ __forceinline__ void tf2x32(unsigned k0, unsigned k1, unsigned& x0, unsigned& x1) {
  unsigned ks2 = k0 ^ k1 ^ 0x1BD11BDAu;
  x0 += k0; x1 += k1;
#define TF_R(r) { x0 += x1; x1 = (x1 << r) | (x1 >> (32 - r)); x1 ^= x0; }
  TF_R(13) TF_R(15) TF_R(26) TF_R(6)   x0 += k1;  x1 += ks2 + 1u;
  TF_R(17) TF_R(29) TF_R(16) TF_R(24)  x0 += ks2; x1 += k0  + 2u;
  TF_R(13) TF_R(15) TF_R(26) TF_R(6)   x0 += k0;  x1 += k1  + 3u;
  TF_R(17) TF_R(29) TF_R(16) TF_R(24)  x0 += k1;  x1 += ks2 + 4u;
  TF_R(13) TF_R(15) TF_R(26) TF_R(6)   x0 += ks2; x1 += k0  + 5u;
#undef TF_R
}

static __device__ __forceinline__ void step_key(int i, unsigned& k0, unsigned& k1) {
#if JAX_PARTITIONABLE
  unsigned x0 = 0u, x1 = (unsigned)i;
  tf2x32(0u, 42u, x0, x1);
  k0 = x0; k1 = x1;
#else
  unsigned w[2];
  for (int wi = 0; wi < 2; wi++) {
    unsigned o = (unsigned)(2*i + wi), x0, x1;
    if (o < 48u) { x0 = o; x1 = 48u + o; tf2x32(0u, 42u, x0, x1); w[wi] = x0; }
    else         { x0 = o - 48u; x1 = o; tf2x32(0u, 42u, x0, x1); w[wi] = x1; }
  }
  k0 = w[0]; k1 = w[1];
#endif
}

static __device__ __forceinline__ unsigned gumbel_bits(unsigned k0, unsigned k1, int b, int v) {
#if JAX_PARTITIONABLE
  unsigned x0 = 0u, x1 = (unsigned)(b*1024 + v);
  tf2x32(k0, k1, x0, x1);
  return x0 ^ x1;
#else
  unsigned jj = (unsigned)((b & 31)*1024 + v);
  unsigned x0 = jj, x1 = 32768u + jj;
  tf2x32(k0, k1, x0, x1);
  return (b < 32) ? x0 : x1;
#endif
}

// ---- positional encoding element ----
static __device__ __forceinline__ float pe_val(int p, int c) {
  const float KC = (float)(-9.210340371976184 / 256.0);
  int j = c >> 1;
  float dv = expf((float)(2*j) * KC);
  float a = (float)p * dv;
  return (c & 1) ? cosf(a) : sinf(a);
}

// ---- per-wave LayerNorm of a 256-float LDS row (call with one full wave) ----
static __device__ __forceinline__ void wave_ln_row(float* row, const float* lw, const float* lb) {
  const int lane = threadIdx.x & 63;
  float x0 = row[lane], x1 = row[lane+64], x2 = row[lane+128], x3 = row[lane+192];
  float s = (x0 + x1) + (x2 + x3);
#pragma unroll
  for (int m = 1; m < 64; m <<= 1) s += __shfl_xor(s, m);
  float mean = s * 0.00390625f;
  float d0 = x0-mean, d1 = x1-mean, d2 = x2-mean, d3 = x3-mean;
  float q = (d0*d0 + d1*d1) + (d2*d2 + d3*d3);
#pragma unroll
  for (int m = 1; m < 64; m <<= 1) q += __shfl_xor(q, m);
  float rs = 1.0f / sqrtf(q * 0.00390625f + 1e-5f);
  row[lane]     = d0*rs*lw[lane]     + lb[lane];
  row[lane+64]  = d1*rs*lw[lane+64]  + lb[lane+64];
  row[lane+128] = d2*rs*lw[lane+128] + lb[lane+128];
  row[lane+192] = d3*rs*lw[lane+192] + lb[lane+192];
}

// ---- transposed coalesced matvec partials: wt is [K][C] (k-major), x in LDS ----
// 32-deep load batches pinned above the consume loop by sched_barrier(0).
// Idle threads (t >= O4*KS) run the optional prefetch descriptor.
// Consumption strictly ascending k, identical FMA pairing -> bitwise identical.
template<int C, int KS, int K>
static __device__ void matvec_t(const float* __restrict__ wt, const float* __restrict__ x,
                                float* __restrict__ part, const PF* pf = nullptr) {
  const int t = threadIdx.x;
  constexpr int O4 = C/4;
  constexpr int KC = K/KS;
  constexpr int BT = (KC < 32) ? KC : 32;
  if (t < O4*KS) {
    const int kc = t / O4, o4 = t - kc*O4;
    const int k0 = kc*KC;
    float4 acc = {0.f,0.f,0.f,0.f};
    const float* wp = wt + k0*C + o4*4;
    for (int kb = 0; kb < KC; kb += BT) {
      float4 w[BT];
#pragma unroll
      for (int j = 0; j < BT; j++) w[j] = *(const float4*)(wp + (kb + j)*C);
      __builtin_amdgcn_sched_barrier(0);
#pragma unroll
      for (int j4 = 0; j4 < BT/4; j4++) {
        float4 xv = *(const float4*)(x + k0 + kb + j4*4);
        float4 a0 = w[j4*4+0], a1 = w[j4*4+1], a2 = w[j4*4+2], a3 = w[j4*4+3];
        acc.x += xv.x*a0.x; acc.y += xv.x*a0.y; acc.z += xv.x*a0.z; acc.w += xv.x*a0.w;
        acc.x += xv.y*a1.x; acc.y += xv.y*a1.y; acc.z += xv.y*a1.z; acc.w += xv.y*a1.w;
        acc.x += xv.z*a2.x; acc.y += xv.z*a2.y; acc.z += xv.z*a2.z; acc.w += xv.z*a2.w;
        acc.x += xv.w*a3.x; acc.y += xv.w*a3.y; acc.z += xv.w*a3.z; acc.w += xv.w*a3.w;
      }
    }
    *(float4*)(part + kc*C + o4*4) = acc;
  } else if (pf) {
    do_pf(pf, t - O4*KS, 512 - O4*KS);
  }
  __syncthreads();
}

// ---- encoder tiled GEMM stage (unchanged) ----
static __device__ void gemm_stage(const float* __restrict__ A, const float* __restrict__ W,
                                  const float* __restrict__ bias, const float* __restrict__ res,
                                  float* __restrict__ out, int R, int C, int K, int relu,
                                  float* sA) {
  const int t = threadIdx.x;
  const bool act = (t < 256);
  const int lane = t & 63, wv = (t >> 6) & 3;
  const int ntc = C >> 6;
  const int ntiles = (R >> 5) * ntc;
  for (int tile = blockIdx.x; tile < ntiles; tile += gridDim.x) {
    const int tr = tile / ntc, tc = tile - tr*ntc;
    const int r0 = tr << 5;
    const int c  = (tc << 6) + lane;
    float acc[8] = {0,0,0,0,0,0,0,0};
    for (int kc = 0; kc < K; kc += 256) {
      __syncthreads();
      if (act) {
#pragma unroll
        for (int u = 0; u < 8; u++) {
          int idx = u*256 + t;
          int rr = idx >> 6, cc = idx & 63;
          ((float4*)sA)[idx] = *(const float4*)(A + (r0+rr)*K + kc + cc*4);
        }
      }
      __syncthreads();
      if (act) {
        const float* wr = W + c*K + kc;
        for (int k = 0; k < 256; k += 4) {
          float4 w4 = *(const float4*)(wr + k);
#pragma unroll
          for (int r = 0; r < 8; r++) {
            float4 a4 = *(const float4*)(sA + (wv*8 + r)*256 + k);
            acc[r] += a4.x*w4.x; acc[r] += a4.y*w4.y; acc[r] += a4.z*w4.z; acc[r] += a4.w*w4.w;
          }
        }
      }
    }
    if (act) {
      float bb = bias ? bias[c] : 0.0f;
#pragma unroll
      for (int r = 0; r < 8; r++) {
        int row = r0 + wv*8 + r;
        float v = acc[r] + bb;
        if (relu) v = fmaxf(v, 0.0f);
        if (res)  v += res[row*C + c];
        out[row*C + c] = v;
      }
    }
  }
}

// ---- encoder LN stage ----
static __device__ void ln_stage(const float* in, const float* lw, const float* lb,
                                float* out, int R) {
  const int lane = threadIdx.x & 63;
  int gw = blockIdx.x*8 + (threadIdx.x >> 6);
  for (int row = gw; row < R; row += gridDim.x*8) {
    const float* ir = in + row*256;
    float x0 = ir[lane], x1 = ir[lane+64], x2 = ir[lane+128], x3 = ir[lane+192];
    float s = (x0 + x1) + (x2 + x3);
#pragma unroll
    for (int m = 1; m < 64; m <<= 1) s += __shfl_xor(s, m);
    float mean = s * 0.00390625f;
    float d0 = x0-mean, d1 = x1-mean, d2 = x2-mean, d3 = x3-mean;
    float q = (d0*d0 + d1*d1) + (d2*d2 + d3*d3);
#pragma unroll
    for (int m = 1; m < 64; m <<= 1) q += __shfl_xor(q, m);
    float rs = 1.0f / sqrtf(q * 0.00390625f + 1e-5f);
    float* orow = out + row*256;
    orow[lane]     = d0*rs*lw[lane]     + lb[lane];
    orow[lane+64]  = d1*rs*lw[lane+64]  + lb[lane+64];
    orow[lane+128] = d2*rs*lw[lane+128] + lb[lane+128];
    orow[lane+192] = d3*rs*lw[lane+192] + lb[lane+192];
  }
}

// ---- encoder attention core (unchanged; K rows in [p][d] layout) ----
static __device__ void attn_core(const float* qd, const float* kb, const float* vb,
                                 int krstride, int kstride, int nk,
                                 float* sc, float* red, float* ao) {
  const int t = threadIdx.x;
  const int r = t >> 5, p0 = t & 31;
  const bool act = (t < 256);
  if (act) {
#pragma unroll
    for (int pass = 0; pass < 2; pass++) {
      int p = pass*32 + p0;
      if (p < nk) {
        const float4* k4 = (const float4*)(kb + r*krstride + p*kstride);
        const float4* q4 = (const float4*)(qd + r*32);
        float a = 0.0f;
#pragma unroll
        for (int d4 = 0; d4 < 8; d4++) {
          float4 kv = k4[d4], qv = q4[d4];
          a += qv.x*kv.x; a += qv.y*kv.y; a += qv.z*kv.z; a += qv.w*kv.w;
        }
        sc[r*48 + p] = a * 0.17677669529663687f;
      }
    }
  }
  __syncthreads();
  if (t < 8) {
    float m = sc[t*48];
    for (int p = 1; p < nk; p++) m = fmaxf(m, sc[t*48 + p]);
    red[t] = m;
  }
  __syncthreads();
  if (act) {
#pragma unroll
    for (int pass = 0; pass < 2; pass++) {
      int p = pass*32 + p0;
      if (p < nk) sc[r*48 + p] = expf(sc[r*48 + p] - red[r]);
    }
  }
  __syncthreads();
  if (t < 8) {
    float s = 0.0f;
    for (int p = 0; p < nk; p++) s += sc[t*48 + p];
    red[8 + t] = s;
  }
  __syncthreads();
  if (act) {
#pragma unroll
    for (int pass = 0; pass < 2; pass++) {
      int p = pass*32 + p0;
      if (p < nk) sc[r*48 + p] = sc[r*48 + p] / red[8 + r];
    }
  }
  __syncthreads();
  if (act) {
    const int d2 = t & 31;
    const float* vr = vb + r*krstride + d2;
    float a = 0.0f;
    for (int p = 0; p < nk; p++) a += sc[r*48 + p] * vr[p*kstride];
    ao[r*32 + d2] = a;
  }
  __syncthreads();
}

static __device__ void enc_attn_stage(const float* QKV, float* AO, float* sm) {
  const int t = threadIdx.x;
  const bool act = (t < 256);
  float* qd  = sm;
  float* sc  = sm + 256;
  float* ao  = sm + 640;
  float* red = sm + 896;
  for (int pi = blockIdx.x; pi < 512; pi += gridDim.x) {
    int b = pi >> 3, h = pi & 7;
    const float* Qb = QKV + b*48*768 + h*32;
    const float* Kb = QKV + b*48*768 + 256 + h*32;
    const float* Vb = QKV + b*48*768 + 512 + h*32;
    for (int qg = 0; qg < 6; qg++) {
      if (act) { int r = t >> 5, d2 = t & 31; qd[r*32 + d2] = Qb[(qg*8 + r)*768 + d2]; }
      __syncthreads();
      attn_core(qd, Kb, Vb, 0, 768, 48, sc, red, ao);
      if (act) { int r = t >> 5, d2 = t & 31; AO[(b*48 + qg*8 + r)*256 + h*32 + d2] = ao[r*32 + d2]; }
      __syncthreads();
    }
  }
}

// ---- decode attention: K transposed [d4][p][4]; V in [p][d] ----
// Threads 256-511 run the prefetch descriptor during the QK section.
// QK/PV batch-load + sched_barrier; accumulation order unchanged.
static __device__ void attn_dec(const float* qd, const float* kt, const float* v,
                                int nk, float* sc, float* red, float* ao, const PF* pf) {
  const int t = threadIdx.x;
  const int r = t >> 5, p0 = t & 31;
  const bool act = (t < 256);
  if (act) {
    const float4* q4 = (const float4*)(qd + r*32);
#pragma unroll
    for (int pass = 0; pass < 2; pass++) {
      int p = pass*32 + p0;
      if (p < nk) {
        const float* kb = kt + r*1536 + p*4;   // r = head; 8 d4-blocks of 192 floats
        float4 kv[8];
#pragma unroll
        for (int j = 0; j < 8; j++) kv[j] = *(const float4*)(kb + j*192);
        __builtin_amdgcn_sched_barrier(0);
        float a = 0.0f;
#pragma unroll
        for (int j = 0; j < 8; j++) {
          float4 qv = q4[j];
          a += qv.x*kv[j].x; a += qv.y*kv[j].y; a += qv.z*kv[j].z; a += qv.w*kv[j].w;
        }
        sc[r*48 + p] = a * 0.17677669529663687f;
      }
    }
  } else if (pf) {
    do_pf(pf, t - 256, 256);
  }
  __syncthreads();
  if (t < 8) {
    const float* scr = sc + t*48;
    float m = scr[0];
    int p = 1;
    for (; p + 8 <= nk; p += 8) {
      float s0=scr[p],s1=scr[p+1],s2=scr[p+2],s3=scr[p+3],
            s4=scr[p+4],s5=scr[p+5],s6=scr[p+6],s7=scr[p+7];
      m=fmaxf(m,s0); m=fmaxf(m,s1); m=fmaxf(m,s2); m=fmaxf(m,s3);
      m=fmaxf(m,s4); m=fmaxf(m,s5); m=fmaxf(m,s6); m=fmaxf(m,s7);
    }
    for (; p < nk; p++) m = fmaxf(m, scr[p]);
    red[t] = m;
  }
  __syncthreads();
  if (act) {
#pragma unroll
    for (int pass = 0; pass < 2; pass++) {
      int p = pass*32 + p0;
      if (p < nk) sc[r*48 + p] = expf(sc[r*48 + p] - red[r]);
    }
  }
  __syncthreads();
  if (t < 8) {
    const float* scr = sc + t*48;
    float s = 0.0f;
    int p = 0;
    for (; p + 8 <= nk; p += 8) {
      float s0=scr[p],s1=scr[p+1],s2=scr[p+2],s3=scr[p+3],
            s4=scr[p+4],s5=scr[p+5],s6=scr[p+6],s7=scr[p+7];
      s+=s0; s+=s1; s+=s2; s+=s3; s+=s4; s+=s5; s+=s6; s+=s7;
    }
    for (; p < nk; p++) s += scr[p];
    red[8 + t] = s;
  }
  __syncthreads();
  if (act) {
#pragma unroll
    for (int pass = 0; pass < 2; pass++) {
      int p = pass*32 + p0;
      if (p < nk) sc[r*48 + p] = sc[r*48 + p] / red[8 + r];
    }
  }
  __syncthreads();
  if (act) {
    const int d2 = t & 31;
    const float* vr = v + r*32 + d2;
    float a = 0.0f;
    int p = 0;
    for (; p + 8 <= nk; p += 8) {
      float vv[8], ss[8];
#pragma unroll
      for (int j = 0; j < 8; j++) vv[j] = vr[(p+j)*256];
#pragma unroll
      for (int j = 0; j < 8; j++) ss[j] = sc[r*48 + p + j];
      __builtin_amdgcn_sched_barrier(0);
#pragma unroll
      for (int j = 0; j < 8; j++) a += ss[j] * vv[j];
    }
    for (; p < nk; p++) a += sc[r*48 + p] * vr[p*256];
    ao[r*32 + d2] = a;
  }
  __syncthreads();
}

// ================= the single persistent kernel =================
__global__ void __launch_bounds__(512, 2)
genrev8_kernel(GParams P) {
  __shared__ float sm[8448];
  float* ws = P.ws;
  const int wg = blockIdx.x;
  const int t  = threadIdx.x;

  // ---- E0: encoder embeddings + pe ----
  if (t < 256) {
    for (int rr = 0; rr < 12; rr++) {
      int row = wg*12 + rr;
      int b = row / 48, s = row % 48;
      int tok = (s < 32) ? P.xc[b*32 + s] : P.xct[b*16 + (s - 32)];
      ws[X_OFF + row*256 + t] = P.emb[(s*1024 + tok)*256 + t] + pe_val(s, t);
    }
  }
  gbar(&g_cntA, &g_genA, 256);

  // ---- encoder: 6 post-norm layers ----
  float* Xp = ws + X_OFF;
  for (int l = 0; l < 6; l++) {
    gemm_stage(Xp, P.ewqkv + l*768*256, P.ebqkv + l*768, nullptr, ws + QKV_OFF, 3072, 768, 256, 0, sm);
    gbar(&g_cntA, &g_genA, 256);
    enc_attn_stage(ws + QKV_OFF, ws + AO_OFF, sm);
    gbar(&g_cntA, &g_genA, 256);
    gemm_stage(ws + AO_OFF, P.ewo + l*256*256, P.ebo + l*256, Xp, ws + RES1_OFF, 3072, 256, 256, 0, sm);
    gbar(&g_cntA, &g_genA, 256);
    ln_stage(ws + RES1_OFF, P.elnw + (l*2 + 0)*256, P.elnb + (l*2 + 0)*256, ws + X1_OFF, 3072);
    gbar(&g_cntA, &g_genA, 256);
    gemm_stage(ws + X1_OFF, P.ew1 + l*1024*256, P.eb1 + l*1024, nullptr, ws + HB_OFF, 3072, 1024, 256, 1, sm);
    gbar(&g_cntA, &g_genA, 256);
    gemm_stage(ws + HB_OFF, P.ew2 + l*256*1024, P.eb2 + l*256, ws + X1_OFF, ws + RES2_OFF, 3072, 256, 1024, 0, sm);
    gbar(&g_cntA, &g_genA, 256);
    ln_stage(ws + RES2_OFF, P.elnw + (l*2 + 1)*256, P.elnb + (l*2 + 1)*256, Xp, 3072);
    gbar(&g_cntA, &g_genA, 256);
  }
  ln_stage(Xp, P.lnfw, P.lnfb, ws + MEM_OFF, 3072);
  gbar(&g_cntA, &g_genA, 256);
  // cross K (plain, temp at PCK) and cross V (final layout) for all 6 layers
  for (int l = 0; l < 6; l++) {
    gemm_stage(ws + MEM_OFF, P.cwqkv + (l*768 + 256)*256, P.cbqkv + l*768 + 256, nullptr,
               ws + PCK_OFF + l*786432, 3072, 256, 256, 0, sm);
    gemm_stage(ws + MEM_OFF, P.cwqkv + (l*768 + 512)*256, P.cbqkv + l*768 + 512, nullptr,
               ws + CV_OFF + l*786432, 3072, 256, 256, 0, sm);
  }
  gbar(&g_cntA, &g_genA, 256);

  // ---- transpose phase: decode weights -> [k][o]; plain cross-K -> [d4][p][4] ----
  {
    const int gt = wg*512 + t;
    const int GT = 256*512;
    for (int idx = gt; idx < 6*256*768; idx += GT) {
      int l = idx / 196608, r = idx - l*196608;
      int k = r / 768, o = r - k*768;
      ws[SWQKVT + idx] = P.swqkv[(l*768 + o)*256 + k];
    }
    for (int idx = gt; idx < 6*65536; idx += GT) {
      int l = idx >> 16, r = idx & 65535, k = r >> 8, o = r & 255;
      ws[SWOT + idx] = P.swo[(l*256 + o)*256 + k];
    }
    for (int idx = gt; idx < 6*65536; idx += GT) {
      int l = idx >> 16, r = idx & 65535, k = r >> 8, o = r & 255;
      ws[CWQT + idx] = P.cwqkv[(l*768 + o)*256 + k];
    }
    for (int idx = gt; idx < 6*65536; idx += GT) {
      int l = idx >> 16, r = idx & 65535, k = r >> 8, o = r & 255;
      ws[CWOT + idx] = P.cwo[(l*256 + o)*256 + k];
    }
    for (int idx = gt; idx < 6*262144; idx += GT) {
      int l = idx >> 18, r = idx & 262143, k = r >> 10, o = r & 1023;
      ws[DW1T + idx] = P.dw1[(l*1024 + o)*256 + k];
    }
    for (int idx = gt; idx < 6*262144; idx += GT) {
      int l = idx >> 18, r = idx & 262143, k = r >> 8, o = r & 255;
      ws[DW2T + idx] = P.dw2[(l*256 + o)*1024 + k];
    }
    // CKT[l][b][d4][p][c] from plain CK[l][b*48+p][d]
    for (int idx = gt; idx < 6*64*48*256; idx += GT) {
      int l = idx / 786432, r = idx - l*786432;
      int b = r / 12288, q = r - b*12288;
      int d4 = q / 192, s2 = q - d4*192;
      int p = s2 >> 2, c = s2 & 3;
      ws[CKT_OFF + idx] = ws[PCK_OFF + l*786432 + (b*48 + p)*256 + d4*4 + c];
    }
    // zero the cohort soft-sync slots (relaxed atomic stores -> LLC)
    unsigned* ssync = (unsigned*)(ws + SSYNC_OFF);
    for (int idx = gt; idx < 3072; idx += GT)
      __hip_atomic_store(&ssync[idx], 0u, __ATOMIC_RELAXED, __HIP_MEMORY_SCOPE_AGENT);
  }
  gbar(&g_cntA, &g_genA, 256);

  // ================= barrier-free per-row decode: WG b owns batch row b =================
  if (wg >= 64) return;
  const int b = wg;
  const int grp = wg & 7;      // round-robin dispatch: same grp -> same XCD-L2
  const int qsl = wg >> 3;     // stagger slice within the 8-WG cohort
  unsigned* ssync = (unsigned*)(ws + SSYNC_OFF);

  float* cur  = sm;           // 256
  float* qv   = sm + 256;     // 256
  float* av   = sm + 512;     // 256
  float* y1   = sm + 768;     // 256
  float* y2   = sm + 1024;    // 256
  float* hbf  = sm + 1280;    // 1024
  float* sc   = sm + 2304;    // 384
  float* red  = sm + 2688;    // 32
  float* y0   = sm + 2720;    // 256
  float* bvv  = sm + 2976;    // 256
  int*   bii  = (int*)(sm + 3232); // 256
  float* part = sm + 3488;    // 2048

  if (t < 256) y0[t] = P.sos[t] + pe_val(0, t);
  __syncthreads();

  for (int i = 0; i < 48; i++) {
    if (t < 256) cur[t] = y0[t];
    __syncthreads();
    for (int l = 0; l < 6; l++) {
      // keep the 8 same-XCD WGs inside the same layer window (weight L2 sharing)
      cohort_sync(ssync + (i*7 + l)*8 + grp);
      const int skt = SKT_OFF + l*786432 + b*12288;
      const int sv  = SV_OFF  + l*786432 + b*12288;
      const int ckt = CKT_OFF + l*786432 + b*12288;
      const int cv  = CV_OFF  + l*786432 + b*12288;
      // prefetch descriptors for this layer
      PF pfqkv;   // during QKV matvec (128 idle threads): own self-KV
      pfqkv.r0 = nullptr; pfqkv.r1 = nullptr; pfqkv.r2 = nullptr;
      pfqkv.rp = ws + skt; pfqkv.np = 12288;
      pfqkv.rp2 = ws + sv; pfqkv.np2 = 12288;
      pfqkv.q = qsl;
      PF pfself;  // during self-attn: next 3 weight blocks (staggered) + own cross-KV
      pfself.r0 = ws + SWOT + l*65536; pfself.n0 = 65536;
      pfself.r1 = ws + CWQT + l*65536; pfself.n1 = 65536;
      pfself.r2 = ws + CWOT + l*65536; pfself.n2 = 65536;
      pfself.rp = ws + ckt; pfself.np = 12288;
      pfself.rp2 = ws + cv; pfself.np2 = 12288;
      pfself.q = qsl;
      PF pfcross; // during cross-attn: FFN weights + next layer's QKV (staggered)
      pfcross.r0 = ws + DW1T + l*262144; pfcross.n0 = 262144;
      pfcross.r1 = ws + DW2T + l*262144; pfcross.n1 = 262144;
      pfcross.r2 = ws + SWQKVT + ((l == 5) ? 0 : (l+1))*196608; pfcross.n2 = 196608;
      pfcross.rp = nullptr; pfcross.rp2 = nullptr;
      pfcross.q = qsl;
      // --- self QKV (transposed, coalesced, 2-way k-split) ---
      matvec_t<768,2,256>(ws + SWQKVT + l*196608, cur, part, &pfqkv);
      for (int o = t; o < 768; o += 512) {
        float v = part[o] + part[768 + o] + P.sbqkv[l*768 + o];
        if (o < 256)      qv[o] = v;
        else if (o < 512) { int d = o - 256; ws[skt + (d>>2)*192 + i*4 + (d&3)] = v; }
        else              ws[sv + i*256 + (o - 512)] = v;
      }
      __syncthreads();
      attn_dec(qv, ws + skt, ws + sv, i + 1, sc, red, av, &pfself);
      // --- self out-proj + residual + LN ---
      matvec_t<256,8,256>(ws + SWOT + l*65536, av, part);
      if (t < 256) {
        float s = part[t];
#pragma unroll
        for (int kc = 1; kc < 8; kc++) s += part[kc*256 + t];
        y1[t] = cur[t] + (s + P.sbo[l*256 + t]);
      }
      __syncthreads();
      if (t < 64) wave_ln_row(y1, P.dlnw + (l*3 + 0)*256, P.dlnb + (l*3 + 0)*256);
      __syncthreads();
      // --- cross q ---
      matvec_t<256,8,256>(ws + CWQT + l*65536, y1, part);
      if (t < 256) {
        float s = part[t];
#pragma unroll
        for (int kc = 1; kc < 8; kc++) s += part[kc*256 + t];
        qv[t] = s + P.cbqkv[l*768 + t];
      }
      __syncthreads();
      attn_dec(qv, ws + ckt, ws + cv, 48, sc, red, av, &pfcross);
      matvec_t<256,8,256>(ws + CWOT + l*65536, av, part);
      if (t < 256) {
        float s = part[t];
#pragma unroll
        for (int kc = 1; kc < 8; kc++) s += part[kc*256 + t];
        y2[t] = y1[t] + (s + P.cbo[l*256 + t]);
      }
      __syncthreads();
      if (t < 64) wave_ln_row(y2, P.dlnw + (l*3 + 1)*256, P.dlnb + (l*3 + 1)*256);
      __syncthreads();
      // --- FFN ---
      matvec_t<1024,2,256>(ws + DW1T + l*262144, y2, part);
      for (int o = t; o < 1024; o += 512)
        hbf[o] = fmaxf(part[o] + part[1024 + o] + P.db1[l*1024 + o], 0.0f);
      __syncthreads();
      matvec_t<256,8,1024>(ws + DW2T + l*262144, hbf, part);
      if (t < 256) {
        float s = part[t];
#pragma unroll
        for (int kc = 1; kc < 8; kc++) s += part[kc*256 + t];
        cur[t] = y2[t] + (s + P.db2[l*256 + t]);
      }
      __syncthreads();
      if (t < 64) wave_ln_row(cur, P.dlnw + (l*3 + 2)*256, P.dlnb + (l*3 + 2)*256);
      __syncthreads();
    }
    // --- final LN (lnf[1]); idle threads prefetch this step's head rows ---
    if (t < 64) {
      wave_ln_row(cur, P.lnfw + 256, P.lnfb + 256);
    } else {
      unsigned acc = pf_slice(P.hw + (size_t)i*262144, 262144, qsl, t - 64, 448);
      asm volatile("" :: "v"(acc));
    }
    __syncthreads();
    // --- head: wave-cooperative rows; 8 float4 loads batched ahead of the
    //     shfl-reduce chains (sched_barrier pins them) ---
    cohort_sync(ssync + (i*7 + 6)*8 + grp);
    {
      const int wv = t >> 6, lane = t & 63;
      const float4 x4 = *(const float4*)(cur + lane*4);
      for (int base = 0; base < 1024; base += 64) {
        float4 wl[8];
#pragma unroll
        for (int u = 0; u < 4; u++) {
          int o = base + u*16 + wv;
          wl[u*2]   = *(const float4*)(P.hw + (size_t)(i*1024 + o)*256 + lane*4);
          wl[u*2+1] = *(const float4*)(P.hw + (size_t)(i*1024 + o + 8)*256 + lane*4);
        }
        __builtin_amdgcn_sched_barrier(0);
#pragma unroll
        for (int u = 0; u < 4; u++) {
          int o = base + u*16 + wv, o2 = o + 8;
          float4 wa = wl[u*2], wb = wl[u*2+1];
          float sa = wa.x*x4.x; sa += wa.y*x4.y; sa += wa.z*x4.z; sa += wa.w*x4.w;
          float sb = wb.x*x4.x; sb += wb.y*x4.y; sb += wb.z*x4.z; sb += wb.w*x4.w;
#pragma unroll
          for (int m = 1; m < 64; m <<= 1) { sa += __shfl_xor(sa, m); sb += __shfl_xor(sb, m); }
          if (lane == 0) {
            hbf[o]  = sa + P.hb[i*1024 + o];
            hbf[o2] = sb + P.hb[i*1024 + o2];
          }
        }
      }
    }
    __syncthreads();
    for (int o = t; o < 1024; o += 512)
      P.out[3072 + i*65536 + b*1024 + o] = hbf[o];
    __syncthreads();
    // --- gumbel-argmax sampling; idle threads prefetch next step's L0 QKV ---
    unsigned k0, k1;
    step_key(i, k0, k1);
    if (t < 256) {
      float bestv = -INFINITY; int besti = 0;
#pragma unroll
      for (int e = 0; e < 4; e++) {
        int v = t*4 + e;
        unsigned bits = gumbel_bits(k0, k1, b, v);
        float f = __uint_as_float((bits >> 9) | 0x3f800000u);
        float u = fmaxf(f - 1.0f, 1.17549435e-38f);
        float g = -logf(-logf(u));
        float z = g + hbf[v] / 0.1f;
        if (z > bestv) { bestv = z; besti = v; }
      }
      bvv[t] = bestv; bii[t] = besti;
    } else {
      unsigned acc = pf_slice(ws + SWQKVT, 196608, qsl, t - 256, 256);
      asm volatile("" :: "v"(acc));
    }
    __syncthreads();
    for (int s = 128; s > 0; s >>= 1) {
      if (t < s) {
        float ov = bvv[t+s]; int oi = bii[t+s];
        if (ov > bvv[t] || (ov == bvv[t] && oi < bii[t])) { bvv[t] = ov; bii[t] = oi; }
      }
      __syncthreads();
    }
    const int ch = bii[0];
    if (t == 0) {
      if (i < 32) P.out[b*32 + i] = (float)ch;
      else        P.out[2048 + b*16 + (i - 32)] = (float)ch;
    }
    if (t < 256) y0[t] = P.emb[(i*1024 + ch)*256 + t] + pe_val(i + 1, t);
    __syncthreads();
  }
}

extern "C" void kernel_launch(void* const* d_in, const int* in_sizes, int n_in,
                              void* d_out, int out_size, void* d_ws, size_t ws_size,
                              hipStream_t stream) {
  (void)in_sizes; (void)n_in; (void)out_size; (void)ws_size;
  GParams p;
  p.xc    = (const int*)  d_in[0];
  p.xct   = (const int*)  d_in[1];
  p.sos   = (const float*)d_in[2];
  p.emb   = (const float*)d_in[3];
  p.hw    = (const float*)d_in[4];
  p.hb    = (const float*)d_in[5];
  p.ewqkv = (const float*)d_in[6];
  p.ebqkv = (const float*)d_in[7];
  p.ewo   = (const float*)d_in[8];
  p.ebo   = (const float*)d_in[9];
  p.ew1   = (const float*)d_in[10];
  p.eb1   = (const float*)d_in[11];
  p.ew2   = (const float*)d_in[12];
  p.eb2   = (const float*)d_in[13];
  p.elnw  = (const float*)d_in[14];
  p.elnb  = (const float*)d_in[15];
  p.swqkv = (const float*)d_in[16];
  p.sbqkv = (const float*)d_in[17];
  p.swo   = (const float*)d_in[18];
  p.sbo   = (const float*)d_in[19];
  p.cwqkv = (const float*)d_in[20];
  p.cbqkv = (const float*)d_in[21];
  p.cwo   = (const float*)d_in[22];
  p.cbo   = (const float*)d_in[23];
  p.dw1   = (const float*)d_in[24];
  p.db1   = (const float*)d_in[25];
  p.dw2   = (const float*)d_in[26];
  p.db2   = (const float*)d_in[27];
  p.dlnw  = (const float*)d_in[28];
  p.dlnb  = (const float*)d_in[29];
  p.lnfw  = (const float*)d_in[30];
  p.lnfb  = (const float*)d_in[31];
  p.out   = (float*)d_out;
  p.ws    = (float*)d_ws;
  hipLaunchKernelGGL(genrev8_kernel, dim3(256), dim3(512), 0, stream, p);
}

// Round 8
// 19749.402 us; speedup vs baseline: 1.0704x; 1.0704x over previous
//
#include <hip/hip_runtime.h>
#include <math.h>

// ===== jax threefry mode: 1 = partitionable (jax >= 0.4.36 default) =====
#define JAX_PARTITIONABLE 1

// ---- model dims: NL=6 D=256 FF=1024 V=1024 S=48 BS=64 H=8 DH=32 ----

// ---- workspace layout (float offsets) ----
static constexpr int SWQKVT  = 0;                        // 6 x [256 k][768 o]
static constexpr int SWOT    = SWQKVT + 6*256*768;       // 1,179,648 ; 6 x [256][256]
static constexpr int CWQT    = SWOT   + 6*256*256;       // 1,572,864
static constexpr int CWOT    = CWQT   + 6*256*256;       // 1,966,080
static constexpr int DW1T    = CWOT   + 6*256*256;       // 2,359,296 ; 6 x [256][1024]
static constexpr int DW2T    = DW1T   + 6*256*1024;      // 3,932,160 ; 6 x [1024][256]
static constexpr int WT_END  = DW2T   + 6*1024*256;      // 5,505,024
static constexpr int CKT_OFF = WT_END;                   // 6 x 64 x [64 d4][48 p][4 c]
static constexpr int CV_OFF  = CKT_OFF + 6*64*48*256;    // 10,223,616 ; [l][b*48+p][256]
static constexpr int SKT_OFF = CV_OFF  + 6*64*48*256;    // 14,942,208
static constexpr int SV_OFF  = SKT_OFF + 6*64*48*256;    // 19,660,800
static constexpr int WS_END  = SV_OFF  + 6*64*48*256;    // 24,379,392 floats = 97.5 MB
// encoder-time aliases (dead before the regions' real use):
static constexpr int X_OFF    = 0;
static constexpr int MEM_OFF  = X_OFF + 3072*256;
static constexpr int QKV_OFF  = SKT_OFF;
static constexpr int AO_OFF   = QKV_OFF + 3072*768;
static constexpr int RES1_OFF = AO_OFF + 3072*256;
static constexpr int X1_OFF   = RES1_OFF + 3072*256;
static constexpr int HB_OFF   = SV_OFF;
static constexpr int RES2_OFF = HB_OFF + 3072*1024;
static constexpr int PCK_OFF  = SKT_OFF;
// ---- cohort soft-sync slots (relaxed-only, performance rendezvous) ----
static constexpr int SSYNC_OFF = WS_END;                 // 3072 uints (12 KB)

struct GParams {
  const int   *xc, *xct;
  const float *sos, *emb, *hw, *hb;
  const float *ewqkv, *ebqkv, *ewo, *ebo, *ew1, *eb1, *ew2, *eb2, *elnw, *elnb;
  const float *swqkv, *sbqkv, *swo, *sbo;
  const float *cwqkv, *cbqkv, *cwo, *cbo;
  const float *dw1, *db1, *dw2, *db2, *dlnw, *dlnb, *lnfw, *lnfb;
  float *out;
  float *ws;
};

// ---- device-global barrier state (generation counters survive graph replays) ----
__device__ unsigned g_cntA = 0, g_genA = 0;

static __device__ __forceinline__ void gbar(unsigned* cnt, unsigned* gen, unsigned nb) {
  __syncthreads();
  if (threadIdx.x == 0) {
    __threadfence();
    unsigned g = __hip_atomic_load(gen, __ATOMIC_RELAXED, __HIP_MEMORY_SCOPE_AGENT);
    unsigned prev = __hip_atomic_fetch_add(cnt, 1u, __ATOMIC_ACQ_REL, __HIP_MEMORY_SCOPE_AGENT);
    if (prev == nb - 1u) {
      __hip_atomic_store(cnt, 0u, __ATOMIC_RELAXED, __HIP_MEMORY_SCOPE_AGENT);
      __threadfence();
      __hip_atomic_store(gen, g + 1u, __ATOMIC_RELEASE, __HIP_MEMORY_SCOPE_AGENT);
    } else {
      while (__hip_atomic_load(gen, __ATOMIC_ACQUIRE, __HIP_MEMORY_SCOPE_AGENT) == g)
        __builtin_amdgcn_s_sleep(1);
      __threadfence();
    }
  }
  __syncthreads();
}

// ---- cohort soft-sync: relaxed-only (NO fences, NO cache invalidation).
static __device__ __forceinline__ void cohort_sync(unsigned* slot) {
  __syncthreads();
  if (threadIdx.x == 0) {
    __hip_atomic_fetch_add(slot, 1u, __ATOMIC_RELAXED, __HIP_MEMORY_SCOPE_AGENT);
    for (int it = 0; it < 64; ++it) {
      if (__hip_atomic_load(slot, __ATOMIC_RELAXED, __HIP_MEMORY_SCOPE_AGENT) >= 8u) break;
      __builtin_amdgcn_s_sleep(1);
    }
  }
  __syncthreads();
}

// ---- threefry2x32 (exact jax rotation/key schedule) ----
static __device__ __forceinline__ void tf2x32(unsigned k0, unsigned k1, unsigned& x0, unsigned& x1) {
  unsigned ks2 = k0 ^ k1 ^ 0x1BD11BDAu;
  x0 += k0; x1 += k1;
#define TF_R(r) { x0 += x1; x1 = (x1 << r) | (x1 >> (32 - r)); x1 ^= x0; }
  TF_R(13) TF_R(15) TF_R(26) TF_R(6)   x0 += k1;  x1 += ks2 + 1u;
  TF_R(17) TF_R(29) TF_R(16) TF_R(24)  x0 += ks2; x1 += k0  + 2u;
  TF_R(13) TF_R(15) TF_R(26) TF_R(6)   x0 += k0;  x1 += k1  + 3u;
  TF_R(17) TF_R(29) TF_R(16) TF_R(24)  x0 += k1;  x1 += ks2 + 4u;
  TF_R(13) TF_R(15) TF_R(26) TF_R(6)   x0 += ks2; x1 += k0  + 5u;
#undef TF_R
}

static __device__ __forceinline__ void step_key(int i, unsigned& k0, unsigned& k1) {
#if JAX_PARTITIONABLE
  unsigned x0 = 0u, x1 = (unsigned)i;
  tf2x32(0u, 42u, x0, x1);
  k0 = x0; k1 = x1;
#else
  unsigned w[2];
  for (int wi = 0; wi < 2; wi++) {
    unsigned o = (unsigned)(2*i + wi), x0, x1;
    if (o < 48u) { x0 = o; x1 = 48u + o; tf2x32(0u, 42u, x0, x1); w[wi] = x0; }
    else         { x0 = o - 48u; x1 = o; tf2x32(0u, 42u, x0, x1); w[wi] = x1; }
  }
  k0 = w[0]; k1 = w[1];
#endif
}

static __device__ __forceinline__ unsigned gumbel_bits(unsigned k0, unsigned k1, int b, int v) {
#if JAX_PARTITIONABLE
  unsigned x0 = 0u, x1 = (unsigned)(b*1024 + v);
  tf2x32(k0, k1, x0, x1);
  return x0 ^ x1;
#else
  unsigned jj = (unsigned)((b & 31)*1024 + v);
  unsigned x0 = jj, x1 = 32768u + jj;
  tf2x32(k0, k1, x0, x1);
  return (b < 32) ? x0 : x1;
#endif
}

// ---- positional encoding element ----
static __device__ __forceinline__ float pe_val(int p, int c) {
  const float KC = (float)(-9.210340371976184 / 256.0);
  int j = c >> 1;
  float dv = expf((float)(2*j) * KC);
  float a = (float)p * dv;
  return (c & 1) ? cosf(a) : sinf(a);
}

// ---- per-wave LayerNorm of a 256-float LDS row (call with one full wave) ----
static __device__ __forceinline__ void wave_ln_row(float* row, const float* lw, const float* lb) {
  const int lane = threadIdx.x & 63;
  float x0 = row[lane], x1 = row[lane+64], x2 = row[lane+128], x3 = row[lane+192];
  float s = (x0 + x1) + (x2 + x3);
#pragma unroll
  for (int m = 1; m < 64; m <<= 1) s += __shfl_xor(s, m);
  float mean = s * 0.00390625f;
  float d0 = x0-mean, d1 = x1-mean, d2 = x2-mean, d3 = x3-mean;
  float q = (d0*d0 + d1*d1) + (d2*d2 + d3*d3);
#pragma unroll
  for (int m = 1; m < 64; m <<= 1) q += __shfl_xor(q, m);
  float rs = 1.0f / sqrtf(q * 0.00390625f + 1e-5f);
  row[lane]     = d0*rs*lw[lane]     + lb[lane];
  row[lane+64]  = d1*rs*lw[lane+64]  + lb[lane+64];
  row[lane+128] = d2*rs*lw[lane+128] + lb[lane+128];
  row[lane+192] = d3*rs*lw[lane+192] + lb[lane+192];
}

// ---- 16-row asm-pipelined global load: 16 global_load_dwordx4 issued
// back-to-back, ONE s_waitcnt vmcnt(0). HW guarantees 16 outstanding per
// thread (rounds 3/4/6: compiler clamps C++-level batches to ~4-6).
// Round-7 lesson: LLVM cannot tie multi-register ("+v" float4) asm operands.
// Legal encoding (rule #18): three separate asm volatile blocks (program-order
// fixed) + sched_barrier(0) after the waitcnt so no consumer FMA can hoist
// into the pending-load window.
template<int C>
static __device__ __forceinline__ void gload16(const float* __restrict__ base,
    float4& w0, float4& w1, float4& w2,  float4& w3,
    float4& w4, float4& w5, float4& w6,  float4& w7,
    float4& w8, float4& w9, float4& w10, float4& w11,
    float4& w12, float4& w13, float4& w14, float4& w15) {
  const float* a0  = base;
  const float* a1  = base + 1*C;
  const float* a2  = base + 2*C;
  const float* a3  = base + 3*C;
  const float* a4  = base + 4*C;
  const float* a5  = base + 5*C;
  const float* a6  = base + 6*C;
  const float* a7  = base + 7*C;
  const float* a8  = base + 8*C;
  const float* a9  = base + 9*C;
  const float* a10 = base + 10*C;
  const float* a11 = base + 11*C;
  const float* a12 = base + 12*C;
  const float* a13 = base + 13*C;
  const float* a14 = base + 14*C;
  const float* a15 = base + 15*C;
  asm volatile(
    "global_load_dwordx4 %0, %8, off\n\t"
    "global_load_dwordx4 %1, %9, off\n\t"
    "global_load_dwordx4 %2, %10, off\n\t"
    "global_load_dwordx4 %3, %11, off\n\t"
    "global_load_dwordx4 %4, %12, off\n\t"
    "global_load_dwordx4 %5, %13, off\n\t"
    "global_load_dwordx4 %6, %14, off\n\t"
    "global_load_dwordx4 %7, %15, off"
    : "=&v"(w0), "=&v"(w1), "=&v"(w2), "=&v"(w3),
      "=&v"(w4), "=&v"(w5), "=&v"(w6), "=&v"(w7)
    : "v"(a0), "v"(a1), "v"(a2), "v"(a3),
      "v"(a4), "v"(a5), "v"(a6), "v"(a7));
  asm volatile(
    "global_load_dwordx4 %0, %8, off\n\t"
    "global_load_dwordx4 %1, %9, off\n\t"
    "global_load_dwordx4 %2, %10, off\n\t"
    "global_load_dwordx4 %3, %11, off\n\t"
    "global_load_dwordx4 %4, %12, off\n\t"
    "global_load_dwordx4 %5, %13, off\n\t"
    "global_load_dwordx4 %6, %14, off\n\t"
    "global_load_dwordx4 %7, %15, off"
    : "=&v"(w8), "=&v"(w9), "=&v"(w10), "=&v"(w11),
      "=&v"(w12), "=&v"(w13), "=&v"(w14), "=&v"(w15)
    : "v"(a8), "v"(a9), "v"(a10), "v"(a11),
      "v"(a12), "v"(a13), "v"(a14), "v"(a15));
  asm volatile("s_waitcnt vmcnt(0)" ::: "memory");
  __builtin_amdgcn_sched_barrier(0);
}

// accumulate 4 weight rows against one x-float4; EXACT original FMA order
#define ACC_ROW4(XV, A, B, CC, D)                                              \
  acc.x += XV.x*A.x;  acc.y += XV.x*A.y;  acc.z += XV.x*A.z;  acc.w += XV.x*A.w;  \
  acc.x += XV.y*B.x;  acc.y += XV.y*B.y;  acc.z += XV.y*B.z;  acc.w += XV.y*B.w;  \
  acc.x += XV.z*CC.x; acc.y += XV.z*CC.y; acc.z += XV.z*CC.z; acc.w += XV.z*CC.w; \
  acc.x += XV.w*D.x;  acc.y += XV.w*D.y;  acc.z += XV.w*D.z;  acc.w += XV.w*D.w;

// ---- transposed coalesced matvec partials: wt is [K][C] (k-major), x in LDS ----
// asm-pipelined 16-row batches; consumption strictly ascending k with the
// original xv-component/FMA pairing -> per-output accumulation bitwise identical.
template<int C, int KS, int K>
static __device__ void matvec_t(const float* __restrict__ wt, const float* __restrict__ x,
                                float* __restrict__ part) {
  const int t = threadIdx.x;
  constexpr int O4 = C/4;
  constexpr int KC = K/KS;
  if (t < O4*KS) {
    const int kc = t / O4, o4 = t - kc*O4;
    const int k0 = kc*KC;
    float4 acc = {0.f,0.f,0.f,0.f};
    const float* wp = wt + k0*C + o4*4;
    for (int kb = 0; kb < KC; kb += 16) {
      float4 w0,w1,w2,w3,w4,w5,w6,w7,w8,w9,w10,w11,w12,w13,w14,w15;
      gload16<C>(wp + kb*C, w0,w1,w2,w3,w4,w5,w6,w7,w8,w9,w10,w11,w12,w13,w14,w15);
      {
        float4 xv = *(const float4*)(x + k0 + kb + 0);
        ACC_ROW4(xv, w0, w1, w2, w3)
      }
      {
        float4 xv = *(const float4*)(x + k0 + kb + 4);
        ACC_ROW4(xv, w4, w5, w6, w7)
      }
      {
        float4 xv = *(const float4*)(x + k0 + kb + 8);
        ACC_ROW4(xv, w8, w9, w10, w11)
      }
      {
        float4 xv = *(const float4*)(x + k0 + kb + 12);
        ACC_ROW4(xv, w12, w13, w14, w15)
      }
    }
    *(float4*)(part + kc*C + o4*4) = acc;
  }
  __syncthreads();
}

// ---- encoder tiled GEMM stage (unchanged) ----
static __device__ void gemm_stage(const float* __restrict__ A, const float* __restrict__ W,
                                  const float* __restrict__ bias, const float* __restrict__ res,
                                  float* __restrict__ out, int R, int C, int K, int relu,
                                  float* sA) {
  const int t = threadIdx.x;
  const bool act = (t < 256);
  const int lane = t & 63, wv = (t >> 6) & 3;
  const int ntc = C >> 6;
  const int ntiles = (R >> 5) * ntc;
  for (int tile = blockIdx.x; tile < ntiles; tile += gridDim.x) {
    const int tr = tile / ntc, tc = tile - tr*ntc;
    const int r0 = tr << 5;
    const int c  = (tc << 6) + lane;
    float acc[8] = {0,0,0,0,0,0,0,0};
    for (int kc = 0; kc < K; kc += 256) {
      __syncthreads();
      if (act) {
#pragma unroll
        for (int u = 0; u < 8; u++) {
          int idx = u*256 + t;
          int rr = idx >> 6, cc = idx & 63;
          ((float4*)sA)[idx] = *(const float4*)(A + (r0+rr)*K + kc + cc*4);
        }
      }
      __syncthreads();
      if (act) {
        const float* wr = W + c*K + kc;
        for (int k = 0; k < 256; k += 4) {
          float4 w4 = *(const float4*)(wr + k);
#pragma unroll
          for (int r = 0; r < 8; r++) {
            float4 a4 = *(const float4*)(sA + (wv*8 + r)*256 + k);
            acc[r] += a4.x*w4.x; acc[r] += a4.y*w4.y; acc[r] += a4.z*w4.z; acc[r] += a4.w*w4.w;
          }
        }
      }
    }
    if (act) {
      float bb = bias ? bias[c] : 0.0f;
#pragma unroll
      for (int r = 0; r < 8; r++) {
        int row = r0 + wv*8 + r;
        float v = acc[r] + bb;
        if (relu) v = fmaxf(v, 0.0f);
        if (res)  v += res[row*C + c];
        out[row*C + c] = v;
      }
    }
  }
}

// ---- encoder LN stage ----
static __device__ void ln_stage(const float* in, const float* lw, const float* lb,
                                float* out, int R) {
  const int lane = threadIdx.x & 63;
  int gw = blockIdx.x*8 + (threadIdx.x >> 6);
  for (int row = gw; row < R; row += gridDim.x*8) {
    const float* ir = in + row*256;
    float x0 = ir[lane], x1 = ir[lane+64], x2 = ir[lane+128], x3 = ir[lane+192];
    float s = (x0 + x1) + (x2 + x3);
#pragma unroll
    for (int m = 1; m < 64; m <<= 1) s += __shfl_xor(s, m);
    float mean = s * 0.00390625f;
    float d0 = x0-mean, d1 = x1-mean, d2 = x2-mean, d3 = x3-mean;
    float q = (d0*d0 + d1*d1) + (d2*d2 + d3*d3);
#pragma unroll
    for (int m = 1; m < 64; m <<= 1) q += __shfl_xor(q, m);
    float rs = 1.0f / sqrtf(q * 0.00390625f + 1e-5f);
    float* orow = out + row*256;
    orow[lane]     = d0*rs*lw[lane]     + lb[lane];
    orow[lane+64]  = d1*rs*lw[lane+64]  + lb[lane+64];
    orow[lane+128] = d2*rs*lw[lane+128] + lb[lane+128];
    orow[lane+192] = d3*rs*lw[lane+192] + lb[lane+192];
  }
}

// ---- encoder attention core (unchanged; K rows in [p][d] layout) ----
static __device__ void attn_core(const float* qd, const float* kb, const float* vb,
                                 int krstride, int kstride, int nk,
                                 float* sc, float* red, float* ao) {
  const int t = threadIdx.x;
  const int r = t >> 5, p0 = t & 31;
  const bool act = (t < 256);
  if (act) {
#pragma unroll
    for (int pass = 0; pass < 2; pass++) {
      int p = pass*32 + p0;
      if (p < nk) {
        const float4* k4 = (const float4*)(kb + r*krstride + p*kstride);
        const float4* q4 = (const float4*)(qd + r*32);
        float a = 0.0f;
#pragma unroll
        for (int d4 = 0; d4 < 8; d4++) {
          float4 kv = k4[d4], qv = q4[d4];
          a += qv.x*kv.x; a += qv.y*kv.y; a += qv.z*kv.z; a += qv.w*kv.w;
        }
        sc[r*48 + p] = a * 0.17677669529663687f;
      }
    }
  }
  __syncthreads();
  if (t < 8) {
    float m = sc[t*48];
    for (int p = 1; p < nk; p++) m = fmaxf(m, sc[t*48 + p]);
    red[t] = m;
  }
  __syncthreads();
  if (act) {
#pragma unroll
    for (int pass = 0; pass < 2; pass++) {
      int p = pass*32 + p0;
      if (p < nk) sc[r*48 + p] = expf(sc[r*48 + p] - red[r]);
    }
  }
  __syncthreads();
  if (t < 8) {
    float s = 0.0f;
    for (int p = 0; p < nk; p++) s += sc[t*48 + p];
    red[8 + t] = s;
  }
  __syncthreads();
  if (act) {
#pragma unroll
    for (int pass = 0; pass < 2; pass++) {
      int p = pass*32 + p0;
      if (p < nk) sc[r*48 + p] = sc[r*48 + p] / red[8 + r];
    }
  }
  __syncthreads();
  if (act) {
    const int d2 = t & 31;
    const float* vr = vb + r*krstride + d2;
    float a = 0.0f;
    for (int p = 0; p < nk; p++) a += sc[r*48 + p] * vr[p*kstride];
    ao[r*32 + d2] = a;
  }
  __syncthreads();
}

static __device__ void enc_attn_stage(const float* QKV, float* AO, float* sm) {
  const int t = threadIdx.x;
  const bool act = (t < 256);
  float* qd  = sm;
  float* sc  = sm + 256;
  float* ao  = sm + 640;
  float* red = sm + 896;
  for (int pi = blockIdx.x; pi < 512; pi += gridDim.x) {
    int b = pi >> 3, h = pi & 7;
    const float* Qb = QKV + b*48*768 + h*32;
    const float* Kb = QKV + b*48*768 + 256 + h*32;
    const float* Vb = QKV + b*48*768 + 512 + h*32;
    for (int qg = 0; qg < 6; qg++) {
      if (act) { int r = t >> 5, d2 = t & 31; qd[r*32 + d2] = Qb[(qg*8 + r)*768 + d2]; }
      __syncthreads();
      attn_core(qd, Kb, Vb, 0, 768, 48, sc, red, ao);
      if (act) { int r = t >> 5, d2 = t & 31; AO[(b*48 + qg*8 + r)*256 + h*32 + d2] = ao[r*32 + d2]; }
      __syncthreads();
    }
  }
}

// ---- decode attention: K transposed [d4][p][4] (coalesced over p); V in [p][d] ----
// QK batch-loads all 8 K-float4s then sched_barrier pins them above the dot;
// PV batch-loads 8 V rows the same way. Accumulation order unchanged.
static __device__ void attn_dec(const float* qd, const float* kt, const float* v,
                                int nk, float* sc, float* red, float* ao) {
  const int t = threadIdx.x;
  const int r = t >> 5, p0 = t & 31;
  const bool act = (t < 256);
  if (act) {
    const float4* q4 = (const float4*)(qd + r*32);
#pragma unroll
    for (int pass = 0; pass < 2; pass++) {
      int p = pass*32 + p0;
      if (p < nk) {
        const float* kb = kt + r*1536 + p*4;   // r = head; 8 d4-blocks of 192 floats
        float4 kv[8];
#pragma unroll
        for (int j = 0; j < 8; j++) kv[j] = *(const float4*)(kb + j*192);
        __builtin_amdgcn_sched_barrier(0);
        float a = 0.0f;
#pragma unroll
        for (int j = 0; j < 8; j++) {
          float4 qv = q4[j];
          a += qv.x*kv[j].x; a += qv.y*kv[j].y; a += qv.z*kv[j].z; a += qv.w*kv[j].w;
        }
        sc[r*48 + p] = a * 0.17677669529663687f;
      }
    }
  }
  __syncthreads();
  if (t < 8) {
    const float* scr = sc + t*48;
    float m = scr[0];
    int p = 1;
    for (; p + 8 <= nk; p += 8) {
      float s0=scr[p],s1=scr[p+1],s2=scr[p+2],s3=scr[p+3],
            s4=scr[p+4],s5=scr[p+5],s6=scr[p+6],s7=scr[p+7];
      m=fmaxf(m,s0); m=fmaxf(m,s1); m=fmaxf(m,s2); m=fmaxf(m,s3);
      m=fmaxf(m,s4); m=fmaxf(m,s5); m=fmaxf(m,s6); m=fmaxf(m,s7);
    }
    for (; p < nk; p++) m = fmaxf(m, scr[p]);
    red[t] = m;
  }
  __syncthreads();
  if (act) {
#pragma unroll
    for (int pass = 0; pass < 2; pass++) {
      int p = pass*32 + p0;
      if (p < nk) sc[r*48 + p] = expf(sc[r*48 + p] - red[r]);
    }
  }
  __syncthreads();
  if (t < 8) {
    const float* scr = sc + t*48;
    float s = 0.0f;
    int p = 0;
    for (; p + 8 <= nk; p += 8) {
      float s0=scr[p],s1=scr[p+1],s2=scr[p+2],s3=scr[p+3],
            s4=scr[p+4],s5=scr[p+5],s6=scr[p+6],s7=scr[p+7];
      s+=s0; s+=s1; s+=s2; s+=s3; s+=s4; s+=s5; s+=s6; s+=s7;
    }
    for (; p < nk; p++) s += scr[p];
    red[8 + t] = s;
  }
  __syncthreads();
  if (act) {
#pragma unroll
    for (int pass = 0; pass < 2; pass++) {
      int p = pass*32 + p0;
      if (p < nk) sc[r*48 + p] = sc[r*48 + p] / red[8 + r];
    }
  }
  __syncthreads();
  if (act) {
    const int d2 = t & 31;
    const float* vr = v + r*32 + d2;
    float a = 0.0f;
    int p = 0;
    for (; p + 8 <= nk; p += 8) {
      float vv[8], ss[8];
#pragma unroll
      for (int j = 0; j < 8; j++) vv[j] = vr[(p+j)*256];
#pragma unroll
      for (int j = 0; j < 8; j++) ss[j] = sc[r*48 + p + j];
      __builtin_amdgcn_sched_barrier(0);
#pragma unroll
      for (int j = 0; j < 8; j++) a += ss[j] * vv[j];
    }
    for (; p < nk; p++) a += sc[r*48 + p] * vr[p*256];
    ao[r*32 + d2] = a;
  }
  __syncthreads();
}

// ================= the single persistent kernel =================
__global__ void __launch_bounds__(512, 2)
genrev10_kernel(GParams P) {
  __shared__ float sm[8448];
  float* ws = P.ws;
  const int wg = blockIdx.x;
  const int t  = threadIdx.x;

  // ---- E0: encoder embeddings + pe ----
  if (t < 256) {
    for (int rr = 0; rr < 12; rr++) {
      int row = wg*12 + rr;
      int b = row / 48, s = row % 48;
      int tok = (s < 32) ? P.xc[b*32 + s] : P.xct[b*16 + (s - 32)];
      ws[X_OFF + row*256 + t] = P.emb[(s*1024 + tok)*256 + t] + pe_val(s, t);
    }
  }
  gbar(&g_cntA, &g_genA, 256);

  // ---- encoder: 6 post-norm layers ----
  float* Xp = ws + X_OFF;
  for (int l = 0; l < 6; l++) {
    gemm_stage(Xp, P.ewqkv + l*768*256, P.ebqkv + l*768, nullptr, ws + QKV_OFF, 3072, 768, 256, 0, sm);
    gbar(&g_cntA, &g_genA, 256);
    enc_attn_stage(ws + QKV_OFF, ws + AO_OFF, sm);
    gbar(&g_cntA, &g_genA, 256);
    gemm_stage(ws + AO_OFF, P.ewo + l*256*256, P.ebo + l*256, Xp, ws + RES1_OFF, 3072, 256, 256, 0, sm);
    gbar(&g_cntA, &g_genA, 256);
    ln_stage(ws + RES1_OFF, P.elnw + (l*2 + 0)*256, P.elnb + (l*2 + 0)*256, ws + X1_OFF, 3072);
    gbar(&g_cntA, &g_genA, 256);
    gemm_stage(ws + X1_OFF, P.ew1 + l*1024*256, P.eb1 + l*1024, nullptr, ws + HB_OFF, 3072, 1024, 256, 1, sm);
    gbar(&g_cntA, &g_genA, 256);
    gemm_stage(ws + HB_OFF, P.ew2 + l*256*1024, P.eb2 + l*256, ws + X1_OFF, ws + RES2_OFF, 3072, 256, 1024, 0, sm);
    gbar(&g_cntA, &g_genA, 256);
    ln_stage(ws + RES2_OFF, P.elnw + (l*2 + 1)*256, P.elnb + (l*2 + 1)*256, Xp, 3072);
    gbar(&g_cntA, &g_genA, 256);
  }
  ln_stage(Xp, P.lnfw, P.lnfb, ws + MEM_OFF, 3072);
  gbar(&g_cntA, &g_genA, 256);
  // cross K (plain, temp at PCK) and cross V (final layout) for all 6 layers
  for (int l = 0; l < 6; l++) {
    gemm_stage(ws + MEM_OFF, P.cwqkv + (l*768 + 256)*256, P.cbqkv + l*768 + 256, nullptr,
               ws + PCK_OFF + l*786432, 3072, 256, 256, 0, sm);
    gemm_stage(ws + MEM_OFF, P.cwqkv + (l*768 + 512)*256, P.cbqkv + l*768 + 512, nullptr,
               ws + CV_OFF + l*786432, 3072, 256, 256, 0, sm);
  }
  gbar(&g_cntA, &g_genA, 256);

  // ---- transpose phase: decode weights -> [k][o]; plain cross-K -> [d4][p][4] ----
  {
    const int gt = wg*512 + t;
    const int GT = 256*512;
    for (int idx = gt; idx < 6*256*768; idx += GT) {
      int l = idx / 196608, r = idx - l*196608;
      int k = r / 768, o = r - k*768;
      ws[SWQKVT + idx] = P.swqkv[(l*768 + o)*256 + k];
    }
    for (int idx = gt; idx < 6*65536; idx += GT) {
      int l = idx >> 16, r = idx & 65535, k = r >> 8, o = r & 255;
      ws[SWOT + idx] = P.swo[(l*256 + o)*256 + k];
    }
    for (int idx = gt; idx < 6*65536; idx += GT) {
      int l = idx >> 16, r = idx & 65535, k = r >> 8, o = r & 255;
      ws[CWQT + idx] = P.cwqkv[(l*768 + o)*256 + k];
    }
    for (int idx = gt; idx < 6*65536; idx += GT) {
      int l = idx >> 16, r = idx & 65535, k = r >> 8, o = r & 255;
      ws[CWOT + idx] = P.cwo[(l*256 + o)*256 + k];
    }
    for (int idx = gt; idx < 6*262144; idx += GT) {
      int l = idx >> 18, r = idx & 262143, k = r >> 10, o = r & 1023;
      ws[DW1T + idx] = P.dw1[(l*1024 + o)*256 + k];
    }
    for (int idx = gt; idx < 6*262144; idx += GT) {
      int l = idx >> 18, r = idx & 262143, k = r >> 8, o = r & 255;
      ws[DW2T + idx] = P.dw2[(l*256 + o)*1024 + k];
    }
    // CKT[l][b][d4][p][c] from plain CK[l][b*48+p][d]
    for (int idx = gt; idx < 6*64*48*256; idx += GT) {
      int l = idx / 786432, r = idx - l*786432;
      int b = r / 12288, q = r - b*12288;
      int d4 = q / 192, s2 = q - d4*192;
      int p = s2 >> 2, c = s2 & 3;
      ws[CKT_OFF + idx] = ws[PCK_OFF + l*786432 + (b*48 + p)*256 + d4*4 + c];
    }
    // zero the cohort soft-sync slots (relaxed atomic stores -> LLC)
    unsigned* ssync = (unsigned*)(ws + SSYNC_OFF);
    for (int idx = gt; idx < 3072; idx += GT)
      __hip_atomic_store(&ssync[idx], 0u, __ATOMIC_RELAXED, __HIP_MEMORY_SCOPE_AGENT);
  }
  gbar(&g_cntA, &g_genA, 256);

  // ================= barrier-free per-row decode: WG b owns batch row b =================
  if (wg >= 64) return;
  const int b = wg;
  const int grp = wg & 7;      // round-robin dispatch: same grp -> same XCD-L2
  unsigned* ssync = (unsigned*)(ws + SSYNC_OFF);

  float* cur  = sm;           // 256
  float* qv   = sm + 256;     // 256
  float* av   = sm + 512;     // 256
  float* y1   = sm + 768;     // 256
  float* y2   = sm + 1024;    // 256
  float* hbf  = sm + 1280;    // 1024
  float* sc   = sm + 2304;    // 384
  float* red  = sm + 2688;    // 32
  float* y0   = sm + 2720;    // 256
  float* bvv  = sm + 2976;    // 256
  int*   bii  = (int*)(sm + 3232); // 256
  float* part = sm + 3488;    // 2048

  if (t < 256) y0[t] = P.sos[t] + pe_val(0, t);
  __syncthreads();

  for (int i = 0; i < 48; i++) {
    if (t < 256) cur[t] = y0[t];
    __syncthreads();
    for (int l = 0; l < 6; l++) {
      // keep the 8 same-XCD WGs inside the same layer window (weight L2 sharing)
      cohort_sync(ssync + (i*7 + l)*8 + grp);
      const int skt = SKT_OFF + l*786432 + b*12288;
      const int sv  = SV_OFF  + l*786432 + b*12288;
      const int ckt = CKT_OFF + l*786432 + b*12288;
      const int cv  = CV_OFF  + l*786432 + b*12288;
      // --- self QKV (transposed, coalesced, 2-way k-split) ---
      matvec_t<768,2,256>(ws + SWQKVT + l*196608, cur, part);
      for (int o = t; o < 768; o += 512) {
        float v = part[o] + part[768 + o] + P.sbqkv[l*768 + o];
        if (o < 256)      qv[o] = v;
        else if (o < 512) { int d = o - 256; ws[skt + (d>>2)*192 + i*4 + (d&3)] = v; }
        else              ws[sv + i*256 + (o - 512)] = v;
      }
      __syncthreads();
      attn_dec(qv, ws + skt, ws + sv, i + 1, sc, red, av);
      // --- self out-proj + residual + LN ---
      matvec_t<256,8,256>(ws + SWOT + l*65536, av, part);
      if (t < 256) {
        float s = part[t];
#pragma unroll
        for (int kc = 1; kc < 8; kc++) s += part[kc*256 + t];
        y1[t] = cur[t] + (s + P.sbo[l*256 + t]);
      }
      __syncthreads();
      if (t < 64) wave_ln_row(y1, P.dlnw + (l*3 + 0)*256, P.dlnb + (l*3 + 0)*256);
      __syncthreads();
      // --- cross q ---
      matvec_t<256,8,256>(ws + CWQT + l*65536, y1, part);
      if (t < 256) {
        float s = part[t];
#pragma unroll
        for (int kc = 1; kc < 8; kc++) s += part[kc*256 + t];
        qv[t] = s + P.cbqkv[l*768 + t];
      }
      __syncthreads();
      attn_dec(qv, ws + ckt, ws + cv, 48, sc, red, av);
      matvec_t<256,8,256>(ws + CWOT + l*65536, av, part);
      if (t < 256) {
        float s = part[t];
#pragma unroll
        for (int kc = 1; kc < 8; kc++) s += part[kc*256 + t];
        y2[t] = y1[t] + (s + P.cbo[l*256 + t]);
      }
      __syncthreads();
      if (t < 64) wave_ln_row(y2, P.dlnw + (l*3 + 1)*256, P.dlnb + (l*3 + 1)*256);
      __syncthreads();
      // --- FFN ---
      matvec_t<1024,2,256>(ws + DW1T + l*262144, y2, part);
      for (int o = t; o < 1024; o += 512)
        hbf[o] = fmaxf(part[o] + part[1024 + o] + P.db1[l*1024 + o], 0.0f);
      __syncthreads();
      matvec_t<256,8,1024>(ws + DW2T + l*262144, hbf, part);
      if (t < 256) {
        float s = part[t];
#pragma unroll
        for (int kc = 1; kc < 8; kc++) s += part[kc*256 + t];
        cur[t] = y2[t] + (s + P.db2[l*256 + t]);
      }
      __syncthreads();
      if (t < 64) wave_ln_row(cur, P.dlnw + (l*3 + 2)*256, P.dlnb + (l*3 + 2)*256);
      __syncthreads();
    }
    // --- final LN (lnf[1]) ---
    if (t < 64) wave_ln_row(cur, P.lnfw + 256, P.lnfb + 256);
    __syncthreads();
    // --- head: wave-cooperative rows; 8 float4 loads batched ahead of the
    //     shfl-reduce chains (sched_barrier pins them) ---
    cohort_sync(ssync + (i*7 + 6)*8 + grp);
    {
      const int wv = t >> 6, lane = t & 63;
      const float4 x4 = *(const float4*)(cur + lane*4);
      for (int base = 0; base < 1024; base += 64) {
        float4 wl[8];
#pragma unroll
        for (int u = 0; u < 4; u++) {
          int o = base + u*16 + wv;
          wl[u*2]   = *(const float4*)(P.hw + (size_t)(i*1024 + o)*256 + lane*4);
          wl[u*2+1] = *(const float4*)(P.hw + (size_t)(i*1024 + o + 8)*256 + lane*4);
        }
        __builtin_amdgcn_sched_barrier(0);
#pragma unroll
        for (int u = 0; u < 4; u++) {
          int o = base + u*16 + wv, o2 = o + 8;
          float4 wa = wl[u*2], wb = wl[u*2+1];
          float sa = wa.x*x4.x; sa += wa.y*x4.y; sa += wa.z*x4.z; sa += wa.w*x4.w;
          float sb = wb.x*x4.x; sb += wb.y*x4.y; sb += wb.z*x4.z; sb += wb.w*x4.w;
#pragma unroll
          for (int m = 1; m < 64; m <<= 1) { sa += __shfl_xor(sa, m); sb += __shfl_xor(sb, m); }
          if (lane == 0) {
            hbf[o]  = sa + P.hb[i*1024 + o];
            hbf[o2] = sb + P.hb[i*1024 + o2];
          }
        }
      }
    }
    __syncthreads();
    for (int o = t; o < 1024; o += 512)
      P.out[3072 + i*65536 + b*1024 + o] = hbf[o];
    __syncthreads();
    // --- gumbel-argmax sampling ---
    unsigned k0, k1;
    step_key(i, k0, k1);
    if (t < 256) {
      float bestv = -INFINITY; int besti = 0;
#pragma unroll
      for (int e = 0; e < 4; e++) {
        int v = t*4 + e;
        unsigned bits = gumbel_bits(k0, k1, b, v);
        float f = __uint_as_float((bits >> 9) | 0x3f800000u);
        float u = fmaxf(f - 1.0f, 1.17549435e-38f);
        float g = -logf(-logf(u));
        float z = g + hbf[v] / 0.1f;
        if (z > bestv) { bestv = z; besti = v; }
      }
      bvv[t] = bestv; bii[t] = besti;
    }
    __syncthreads();
    for (int s = 128; s > 0; s >>= 1) {
      if (t < s) {
        float ov = bvv[t+s]; int oi = bii[t+s];
        if (ov > bvv[t] || (ov == bvv[t] && oi < bii[t])) { bvv[t] = ov; bii[t] = oi; }
      }
      __syncthreads();
    }
    const int ch = bii[0];
    if (t == 0) {
      if (i < 32) P.out[b*32 + i] = (float)ch;
      else        P.out[2048 + b*16 + (i - 32)] = (float)ch;
    }
    if (t < 256) y0[t] = P.emb[(i*1024 + ch)*256 + t] + pe_val(i + 1, t);
    __syncthreads();
  }
}

extern "C" void kernel_launch(void* const* d_in, const int* in_sizes, int n_in,
                              void* d_out, int out_size, void* d_ws, size_t ws_size,
                              hipStream_t stream) {
  (void)in_sizes; (void)n_in; (void)out_size; (void)ws_size;
  GParams p;
  p.xc    = (const int*)  d_in[0];
  p.xct   = (const int*)  d_in[1];
  p.sos   = (const float*)d_in[2];
  p.emb   = (const float*)d_in[3];
  p.hw    = (const float*)d_in[4];
  p.hb    = (const float*)d_in[5];
  p.ewqkv = (const float*)d_in[6];
  p.ebqkv = (const float*)d_in[7];
  p.ewo   = (const float*)d_in[8];
  p.ebo   = (const float*)d_in[9];
  p.ew1   = (const float*)d_in[10];
  p.eb1   = (const float*)d_in[11];
  p.ew2   = (const float*)d_in[12];
  p.eb2   = (const float*)d_in[13];
  p.elnw  = (const float*)d_in[14];
  p.elnb  = (const float*)d_in[15];
  p.swqkv = (const float*)d_in[16];
  p.sbqkv = (const float*)d_in[17];
  p.swo   = (const float*)d_in[18];
  p.sbo   = (const float*)d_in[19];
  p.cwqkv = (const float*)d_in[20];
  p.cbqkv = (const float*)d_in[21];
  p.cwo   = (const float*)d_in[22];
  p.cbo   = (const float*)d_in[23];
  p.dw1   = (const float*)d_in[24];
  p.db1   = (const float*)d_in[25];
  p.dw2   = (const float*)d_in[26];
  p.db2   = (const float*)d_in[27];
  p.dlnw  = (const float*)d_in[28];
  p.dlnb  = (const float*)d_in[29];
  p.lnfw  = (const float*)d_in[30];
  p.lnfb  = (const float*)d_in[31];
  p.out   = (float*)d_out;
  p.ws    = (float*)d_ws;
  hipLaunchKernelGGL(genrev10_kernel, dim3(256), dim3(512), 0, stream, p);
}

// Round 10
// 19718.369 us; speedup vs baseline: 1.0721x; 1.0016x over previous
//
#include <hip/hip_runtime.h>
#include <math.h>

// ===== jax threefry mode: 1 = partitionable (jax >= 0.4.36 default) =====
#define JAX_PARTITIONABLE 1

// ---- model dims: NL=6 D=256 FF=1024 V=1024 S=48 BS=64 H=8 DH=32 ----

// ---- workspace layout (float offsets) ----
static constexpr int SWQKVT  = 0;                        // 6 x [256 k][768 o]
static constexpr int SWOT    = SWQKVT + 6*256*768;       // 1,179,648 ; 6 x [256][256]
static constexpr int CWQT    = SWOT   + 6*256*256;       // 1,572,864
static constexpr int CWOT    = CWQT   + 6*256*256;       // 1,966,080
static constexpr int DW1T    = CWOT   + 6*256*256;       // 2,359,296 ; 6 x [256][1024]
static constexpr int DW2T    = DW1T   + 6*256*1024;      // 3,932,160 ; 6 x [1024][256]
static constexpr int WT_END  = DW2T   + 6*1024*256;      // 5,505,024
static constexpr int CKT_OFF = WT_END;                   // 6 x 64 x [64 d4][48 p][4 c]
static constexpr int CV_OFF  = CKT_OFF + 6*64*48*256;    // 10,223,616 ; [l][b*48+p][256]
static constexpr int SKT_OFF = CV_OFF  + 6*64*48*256;    // 14,942,208
static constexpr int SV_OFF  = SKT_OFF + 6*64*48*256;    // 19,660,800
static constexpr int WS_END  = SV_OFF  + 6*64*48*256;    // 24,379,392 floats = 97.5 MB
// encoder-time aliases (dead before the regions' real use):
static constexpr int X_OFF    = 0;
static constexpr int MEM_OFF  = X_OFF + 3072*256;
static constexpr int QKV_OFF  = SKT_OFF;
static constexpr int AO_OFF   = QKV_OFF + 3072*768;
static constexpr int RES1_OFF = AO_OFF + 3072*256;
static constexpr int X1_OFF   = RES1_OFF + 3072*256;
static constexpr int HB_OFF   = SV_OFF;
static constexpr int RES2_OFF = HB_OFF + 3072*1024;
static constexpr int PCK_OFF  = SKT_OFF;
// ---- cohort soft-sync slots (relaxed-only, performance rendezvous) ----
static constexpr int SSYNC_OFF = WS_END;                 // 3072 uints (12 KB)

struct GParams {
  const int   *xc, *xct;
  const float *sos, *emb, *hw, *hb;
  const float *ewqkv, *ebqkv, *ewo, *ebo, *ew1, *eb1, *ew2, *eb2, *elnw, *elnb;
  const float *swqkv, *sbqkv, *swo, *sbo;
  const float *cwqkv, *cbqkv, *cwo, *cbo;
  const float *dw1, *db1, *dw2, *db2, *dlnw, *dlnb, *lnfw, *lnfb;
  float *out;
  float *ws;
};

// ---- device-global barrier state (generation counters survive graph replays) ----
__device__ unsigned g_cntA = 0, g_genA = 0;

static __device__ __forceinline__ void gbar(unsigned* cnt, unsigned* gen, unsigned nb) {
  __syncthreads();
  if (threadIdx.x == 0) {
    __threadfence();
    unsigned g = __hip_atomic_load(gen, __ATOMIC_RELAXED, __HIP_MEMORY_SCOPE_AGENT);
    unsigned prev = __hip_atomic_fetch_add(cnt, 1u, __ATOMIC_ACQ_REL, __HIP_MEMORY_SCOPE_AGENT);
    if (prev == nb - 1u) {
      __hip_atomic_store(cnt, 0u, __ATOMIC_RELAXED, __HIP_MEMORY_SCOPE_AGENT);
      __threadfence();
      __hip_atomic_store(gen, g + 1u, __ATOMIC_RELEASE, __HIP_MEMORY_SCOPE_AGENT);
    } else {
      while (__hip_atomic_load(gen, __ATOMIC_ACQUIRE, __HIP_MEMORY_SCOPE_AGENT) == g)
        __builtin_amdgcn_s_sleep(1);
      __threadfence();
    }
  }
  __syncthreads();
}

// ---- cohort soft-sync: relaxed-only (NO fences, NO cache invalidation).
static __device__ __forceinline__ void cohort_sync(unsigned* slot) {
  __syncthreads();
  if (threadIdx.x == 0) {
    __hip_atomic_fetch_add(slot, 1u, __ATOMIC_RELAXED, __HIP_MEMORY_SCOPE_AGENT);
    for (int it = 0; it < 64; ++it) {
      if (__hip_atomic_load(slot, __ATOMIC_RELAXED, __HIP_MEMORY_SCOPE_AGENT) >= 8u) break;
      __builtin_amdgcn_s_sleep(1);
    }
  }
  __syncthreads();
}

// ---- threefry2x32 (exact jax rotation/key schedule) ----
static __device__ __forceinline__ void tf2x32(unsigned k0, unsigned k1, unsigned& x0, unsigned& x1) {
  unsigned ks2 = k0 ^ k1 ^ 0x1BD11BDAu;
  x0 += k0; x1 += k1;
#define TF_R(r) { x0 += x1; x1 = (x1 << r) | (x1 >> (32 - r)); x1 ^= x0; }
  TF_R(13) TF_R(15) TF_R(26) TF_R(6)   x0 += k1;  x1 += ks2 + 1u;
  TF_R(17) TF_R(29) TF_R(16) TF_R(24)  x0 += ks2; x1 += k0  + 2u;
  TF_R(13) TF_R(15) TF_R(26) TF_R(6)   x0 += k0;  x1 += k1  + 3u;
  TF_R(17) TF_R(29) TF_R(16) TF_R(24)  x0 += k1;  x1 += ks2 + 4u;
  TF_R(13) TF_R(15) TF_R(26) TF_R(6)   x0 += ks2; x1 += k0  + 5u;
#undef TF_R
}

static __device__ __forceinline__ void step_key(int i, unsigned& k0, unsigned& k1) {
#if JAX_PARTITIONABLE
  unsigned x0 = 0u, x1 = (unsigned)i;
  tf2x32(0u, 42u, x0, x1);
  k0 = x0; k1 = x1;
#else
  unsigned w[2];
  for (int wi = 0; wi < 2; wi++) {
    unsigned o = (unsigned)(2*i + wi), x0, x1;
    if (o < 48u) { x0 = o; x1 = 48u + o; tf2x32(0u, 42u, x0, x1); w[wi] = x0; }
    else         { x0 = o - 48u; x1 = o; tf2x32(0u, 42u, x0, x1); w[wi] = x1; }
  }
  k0 = w[0]; k1 = w[1];
#endif
}

static __device__ __forceinline__ unsigned gumbel_bits(unsigned k0, unsigned k1, int b, int v) {
#if JAX_PARTITIONABLE
  unsigned x0 = 0u, x1 = (unsigned)(b*1024 + v);
  tf2x32(k0, k1, x0, x1);
  return x0 ^ x1;
#else
  unsigned jj = (unsigned)((b & 31)*1024 + v);
  unsigned x0 = jj, x1 = 32768u + jj;
  tf2x32(k0, k1, x0, x1);
  return (b < 32) ? x0 : x1;
#endif
}

// ---- positional encoding element ----
static __device__ __forceinline__ float pe_val(int p, int c) {
  const float KC = (float)(-9.210340371976184 / 256.0);
  int j = c >> 1;
  float dv = expf((float)(2*j) * KC);
  float a = (float)p * dv;
  return (c & 1) ? cosf(a) : sinf(a);
}

// ---- per-wave LayerNorm of a 256-float LDS row (call with one full wave) ----
static __device__ __forceinline__ void wave_ln_row(float* row, const float* lw, const float* lb) {
  const int lane = threadIdx.x & 63;
  float x0 = row[lane], x1 = row[lane+64], x2 = row[lane+128], x3 = row[lane+192];
  float s = (x0 + x1) + (x2 + x3);
#pragma unroll
  for (int m = 1; m < 64; m <<= 1) s += __shfl_xor(s, m);
  float mean = s * 0.00390625f;
  float d0 = x0-mean, d1 = x1-mean, d2 = x2-mean, d3 = x3-mean;
  float q = (d0*d0 + d1*d1) + (d2*d2 + d3*d3);
#pragma unroll
  for (int m = 1; m < 64; m <<= 1) q += __shfl_xor(q, m);
  float rs = 1.0f / sqrtf(q * 0.00390625f + 1e-5f);
  row[lane]     = d0*rs*lw[lane]     + lb[lane];
  row[lane+64]  = d1*rs*lw[lane+64]  + lb[lane+64];
  row[lane+128] = d2*rs*lw[lane+128] + lb[lane+128];
  row[lane+192] = d3*rs*lw[lane+192] + lb[lane+192];
}

// ---- 16-row asm-pipelined global load: 16 global_load_dwordx4 issued
// back-to-back, ONE s_waitcnt vmcnt(0) (full drain — the ONLY validated form;
// round-9 counted-vmcnt pipelining crashed: compiler-inserted vmcnt-counting
// ops break the count). Two 8-load asm blocks (round-7: no tied float4
// operands); sched_barrier(0) after the wait (rule #18 fence).
template<int C>
static __device__ __forceinline__ void gload16(const float* __restrict__ base,
    float4& w0, float4& w1, float4& w2,  float4& w3,
    float4& w4, float4& w5, float4& w6,  float4& w7,
    float4& w8, float4& w9, float4& w10, float4& w11,
    float4& w12, float4& w13, float4& w14, float4& w15) {
  const float* a0  = base;
  const float* a1  = base + 1*C;
  const float* a2  = base + 2*C;
  const float* a3  = base + 3*C;
  const float* a4  = base + 4*C;
  const float* a5  = base + 5*C;
  const float* a6  = base + 6*C;
  const float* a7  = base + 7*C;
  const float* a8  = base + 8*C;
  const float* a9  = base + 9*C;
  const float* a10 = base + 10*C;
  const float* a11 = base + 11*C;
  const float* a12 = base + 12*C;
  const float* a13 = base + 13*C;
  const float* a14 = base + 14*C;
  const float* a15 = base + 15*C;
  asm volatile(
    "global_load_dwordx4 %0, %8, off\n\t"
    "global_load_dwordx4 %1, %9, off\n\t"
    "global_load_dwordx4 %2, %10, off\n\t"
    "global_load_dwordx4 %3, %11, off\n\t"
    "global_load_dwordx4 %4, %12, off\n\t"
    "global_load_dwordx4 %5, %13, off\n\t"
    "global_load_dwordx4 %6, %14, off\n\t"
    "global_load_dwordx4 %7, %15, off"
    : "=&v"(w0), "=&v"(w1), "=&v"(w2), "=&v"(w3),
      "=&v"(w4), "=&v"(w5), "=&v"(w6), "=&v"(w7)
    : "v"(a0), "v"(a1), "v"(a2), "v"(a3),
      "v"(a4), "v"(a5), "v"(a6), "v"(a7));
  asm volatile(
    "global_load_dwordx4 %0, %8, off\n\t"
    "global_load_dwordx4 %1, %9, off\n\t"
    "global_load_dwordx4 %2, %10, off\n\t"
    "global_load_dwordx4 %3, %11, off\n\t"
    "global_load_dwordx4 %4, %12, off\n\t"
    "global_load_dwordx4 %5, %13, off\n\t"
    "global_load_dwordx4 %6, %14, off\n\t"
    "global_load_dwordx4 %7, %15, off"
    : "=&v"(w8), "=&v"(w9), "=&v"(w10), "=&v"(w11),
      "=&v"(w12), "=&v"(w13), "=&v"(w14), "=&v"(w15)
    : "v"(a8), "v"(a9), "v"(a10), "v"(a11),
      "v"(a12), "v"(a13), "v"(a14), "v"(a15));
  asm volatile("s_waitcnt vmcnt(0)" ::: "memory");
  __builtin_amdgcn_sched_barrier(0);
}

// accumulate 4 weight rows against one x-float4; EXACT original FMA order
#define ACC_ROW4(XV, A, B, CC, D)                                              \
  acc.x += XV.x*A.x;  acc.y += XV.x*A.y;  acc.z += XV.x*A.z;  acc.w += XV.x*A.w;  \
  acc.x += XV.y*B.x;  acc.y += XV.y*B.y;  acc.z += XV.y*B.z;  acc.w += XV.y*B.w;  \
  acc.x += XV.z*CC.x; acc.y += XV.z*CC.y; acc.z += XV.z*CC.z; acc.w += XV.z*CC.w; \
  acc.x += XV.w*D.x;  acc.y += XV.w*D.y;  acc.z += XV.w*D.z;  acc.w += XV.w*D.w;

// ---- transposed coalesced matvec partials: wt is [K][C] (k-major), x in LDS ----
// asm-pipelined 16-row batches (round-8 proven form); consumption strictly
// ascending k with the original FMA pairing -> bitwise identical.
template<int C, int KS, int K>
static __device__ void matvec_t(const float* __restrict__ wt, const float* __restrict__ x,
                                float* __restrict__ part) {
  const int t = threadIdx.x;
  constexpr int O4 = C/4;
  constexpr int KC = K/KS;
  if (t < O4*KS) {
    const int kc = t / O4, o4 = t - kc*O4;
    const int k0 = kc*KC;
    float4 acc = {0.f,0.f,0.f,0.f};
    const float* wp = wt + k0*C + o4*4;
    for (int kb = 0; kb < KC; kb += 16) {
      float4 w0,w1,w2,w3,w4,w5,w6,w7,w8,w9,w10,w11,w12,w13,w14,w15;
      gload16<C>(wp + kb*C, w0,w1,w2,w3,w4,w5,w6,w7,w8,w9,w10,w11,w12,w13,w14,w15);
      {
        float4 xv = *(const float4*)(x + k0 + kb + 0);
        ACC_ROW4(xv, w0, w1, w2, w3)
      }
      {
        float4 xv = *(const float4*)(x + k0 + kb + 4);
        ACC_ROW4(xv, w4, w5, w6, w7)
      }
      {
        float4 xv = *(const float4*)(x + k0 + kb + 8);
        ACC_ROW4(xv, w8, w9, w10, w11)
      }
      {
        float4 xv = *(const float4*)(x + k0 + kb + 12);
        ACC_ROW4(xv, w12, w13, w14, w15)
      }
    }
    *(float4*)(part + kc*C + o4*4) = acc;
  }
  __syncthreads();
}

// ---- encoder tiled GEMM stage (unchanged) ----
static __device__ void gemm_stage(const float* __restrict__ A, const float* __restrict__ W,
                                  const float* __restrict__ bias, const float* __restrict__ res,
                                  float* __restrict__ out, int R, int C, int K, int relu,
                                  float* sA) {
  const int t = threadIdx.x;
  const bool act = (t < 256);
  const int lane = t & 63, wv = (t >> 6) & 3;
  const int ntc = C >> 6;
  const int ntiles = (R >> 5) * ntc;
  for (int tile = blockIdx.x; tile < ntiles; tile += gridDim.x) {
    const int tr = tile / ntc, tc = tile - tr*ntc;
    const int r0 = tr << 5;
    const int c  = (tc << 6) + lane;
    float acc[8] = {0,0,0,0,0,0,0,0};
    for (int kc = 0; kc < K; kc += 256) {
      __syncthreads();
      if (act) {
#pragma unroll
        for (int u = 0; u < 8; u++) {
          int idx = u*256 + t;
          int rr = idx >> 6, cc = idx & 63;
          ((float4*)sA)[idx] = *(const float4*)(A + (r0+rr)*K + kc + cc*4);
        }
      }
      __syncthreads();
      if (act) {
        const float* wr = W + c*K + kc;
        for (int k = 0; k < 256; k += 4) {
          float4 w4 = *(const float4*)(wr + k);
#pragma unroll
          for (int r = 0; r < 8; r++) {
            float4 a4 = *(const float4*)(sA + (wv*8 + r)*256 + k);
            acc[r] += a4.x*w4.x; acc[r] += a4.y*w4.y; acc[r] += a4.z*w4.z; acc[r] += a4.w*w4.w;
          }
        }
      }
    }
    if (act) {
      float bb = bias ? bias[c] : 0.0f;
#pragma unroll
      for (int r = 0; r < 8; r++) {
        int row = r0 + wv*8 + r;
        float v = acc[r] + bb;
        if (relu) v = fmaxf(v, 0.0f);
        if (res)  v += res[row*C + c];
        out[row*C + c] = v;
      }
    }
  }
}

// ---- encoder LN stage ----
static __device__ void ln_stage(const float* in, const float* lw, const float* lb,
                                float* out, int R) {
  const int lane = threadIdx.x & 63;
  int gw = blockIdx.x*8 + (threadIdx.x >> 6);
  for (int row = gw; row < R; row += gridDim.x*8) {
    const float* ir = in + row*256;
    float x0 = ir[lane], x1 = ir[lane+64], x2 = ir[lane+128], x3 = ir[lane+192];
    float s = (x0 + x1) + (x2 + x3);
#pragma unroll
    for (int m = 1; m < 64; m <<= 1) s += __shfl_xor(s, m);
    float mean = s * 0.00390625f;
    float d0 = x0-mean, d1 = x1-mean, d2 = x2-mean, d3 = x3-mean;
    float q = (d0*d0 + d1*d1) + (d2*d2 + d3*d3);
#pragma unroll
    for (int m = 1; m < 64; m <<= 1) q += __shfl_xor(q, m);
    float rs = 1.0f / sqrtf(q * 0.00390625f + 1e-5f);
    float* orow = out + row*256;
    orow[lane]     = d0*rs*lw[lane]     + lb[lane];
    orow[lane+64]  = d1*rs*lw[lane+64]  + lb[lane+64];
    orow[lane+128] = d2*rs*lw[lane+128] + lb[lane+128];
    orow[lane+192] = d3*rs*lw[lane+192] + lb[lane+192];
  }
}

// ---- encoder attention core (unchanged; K rows in [p][d] layout) ----
static __device__ void attn_core(const float* qd, const float* kb, const float* vb,
                                 int krstride, int kstride, int nk,
                                 float* sc, float* red, float* ao) {
  const int t = threadIdx.x;
  const int r = t >> 5, p0 = t & 31;
  const bool act = (t < 256);
  if (act) {
#pragma unroll
    for (int pass = 0; pass < 2; pass++) {
      int p = pass*32 + p0;
      if (p < nk) {
        const float4* k4 = (const float4*)(kb + r*krstride + p*kstride);
        const float4* q4 = (const float4*)(qd + r*32);
        float a = 0.0f;
#pragma unroll
        for (int d4 = 0; d4 < 8; d4++) {
          float4 kv = k4[d4], qv = q4[d4];
          a += qv.x*kv.x; a += qv.y*kv.y; a += qv.z*kv.z; a += qv.w*kv.w;
        }
        sc[r*48 + p] = a * 0.17677669529663687f;
      }
    }
  }
  __syncthreads();
  if (t < 8) {
    float m = sc[t*48];
    for (int p = 1; p < nk; p++) m = fmaxf(m, sc[t*48 + p]);
    red[t] = m;
  }
  __syncthreads();
  if (act) {
#pragma unroll
    for (int pass = 0; pass < 2; pass++) {
      int p = pass*32 + p0;
      if (p < nk) sc[r*48 + p] = expf(sc[r*48 + p] - red[r]);
    }
  }
  __syncthreads();
  if (t < 8) {
    float s = 0.0f;
    for (int p = 0; p < nk; p++) s += sc[t*48 + p];
    red[8 + t] = s;
  }
  __syncthreads();
  if (act) {
#pragma unroll
    for (int pass = 0; pass < 2; pass++) {
      int p = pass*32 + p0;
      if (p < nk) sc[r*48 + p] = sc[r*48 + p] / red[8 + r];
    }
  }
  __syncthreads();
  if (act) {
    const int d2 = t & 31;
    const float* vr = vb + r*krstride + d2;
    float a = 0.0f;
    for (int p = 0; p < nk; p++) a += sc[r*48 + p] * vr[p*kstride];
    ao[r*32 + d2] = a;
  }
  __syncthreads();
}

static __device__ void enc_attn_stage(const float* QKV, float* AO, float* sm) {
  const int t = threadIdx.x;
  const bool act = (t < 256);
  float* qd  = sm;
  float* sc  = sm + 256;
  float* ao  = sm + 640;
  float* red = sm + 896;
  for (int pi = blockIdx.x; pi < 512; pi += gridDim.x) {
    int b = pi >> 3, h = pi & 7;
    const float* Qb = QKV + b*48*768 + h*32;
    const float* Kb = QKV + b*48*768 + 256 + h*32;
    const float* Vb = QKV + b*48*768 + 512 + h*32;
    for (int qg = 0; qg < 6; qg++) {
      if (act) { int r = t >> 5, d2 = t & 31; qd[r*32 + d2] = Qb[(qg*8 + r)*768 + d2]; }
      __syncthreads();
      attn_core(qd, Kb, Vb, 0, 768, 48, sc, red, ao);
      if (act) { int r = t >> 5, d2 = t & 31; AO[(b*48 + qg*8 + r)*256 + h*32 + d2] = ao[r*32 + d2]; }
      __syncthreads();
    }
  }
}

// ---- decode attention: K transposed [d4][p][4] (coalesced over p); V in [p][d] ----
// Scores kept in REGISTERS through max+exp: fmax is exact/commutative, so the
// 32-lane shfl_xor max is bitwise identical to the serial scan; exp(a-m) applied
// to the same f32 values. Only e-values hit LDS. The ordered sum (rounding-
// sensitive) stays serial. 4 syncs instead of 6. QK/PV loads C++-batched with
// sched_barrier pinning (round-8 proven).
static __device__ void attn_dec(const float* qd, const float* kt, const float* v,
                                int nk, float* sc, float* red, float* ao) {
  const int t = threadIdx.x;
  const int r = t >> 5, p0 = t & 31;
  const bool act = (t < 256);
  if (act) {
    const float4* q4 = (const float4*)(qd + r*32);
    float a0 = -INFINITY, a1 = -INFINITY;
    if (p0 < nk) {
      const float* kb = kt + r*1536 + p0*4;   // r = head; 8 d4-blocks of 192 floats
      float4 kv[8];
#pragma unroll
      for (int j = 0; j < 8; j++) kv[j] = *(const float4*)(kb + j*192);
      __builtin_amdgcn_sched_barrier(0);
      float a = 0.0f;
#pragma unroll
      for (int j = 0; j < 8; j++) {
        float4 qv = q4[j];
        a += qv.x*kv[j].x; a += qv.y*kv[j].y; a += qv.z*kv[j].z; a += qv.w*kv[j].w;
      }
      a0 = a * 0.17677669529663687f;
    }
    if (32 + p0 < nk) {
      const float* kb = kt + r*1536 + (32 + p0)*4;
      float4 kv[8];
#pragma unroll
      for (int j = 0; j < 8; j++) kv[j] = *(const float4*)(kb + j*192);
      __builtin_amdgcn_sched_barrier(0);
      float a = 0.0f;
#pragma unroll
      for (int j = 0; j < 8; j++) {
        float4 qv = q4[j];
        a += qv.x*kv[j].x; a += qv.y*kv[j].y; a += qv.z*kv[j].z; a += qv.w*kv[j].w;
      }
      a1 = a * 0.17677669529663687f;
    }
    // in-head (32-lane) max: xor masks 1..16 stay within each 32-lane half
    float m = fmaxf(a0, a1);
#pragma unroll
    for (int mm = 1; mm < 32; mm <<= 1) m = fmaxf(m, __shfl_xor(m, mm));
    if (p0 < nk)      sc[r*48 + p0]      = expf(a0 - m);
    if (32 + p0 < nk) sc[r*48 + 32 + p0] = expf(a1 - m);
  }
  __syncthreads();
  if (t < 8) {
    const float* scr = sc + t*48;
    float s = 0.0f;
    int p = 0;
    for (; p + 8 <= nk; p += 8) {
      float s0=scr[p],s1=scr[p+1],s2=scr[p+2],s3=scr[p+3],
            s4=scr[p+4],s5=scr[p+5],s6=scr[p+6],s7=scr[p+7];
      s+=s0; s+=s1; s+=s2; s+=s3; s+=s4; s+=s5; s+=s6; s+=s7;
    }
    for (; p < nk; p++) s += scr[p];
    red[8 + t] = s;
  }
  __syncthreads();
  if (act) {
    if (p0 < nk)      sc[r*48 + p0]      = sc[r*48 + p0]      / red[8 + r];
    if (32 + p0 < nk) sc[r*48 + 32 + p0] = sc[r*48 + 32 + p0] / red[8 + r];
  }
  __syncthreads();
  if (act) {
    const int d2 = t & 31;
    const float* vr = v + r*32 + d2;
    float a = 0.0f;
    int p = 0;
    for (; p + 8 <= nk; p += 8) {
      float vv[8], ss[8];
#pragma unroll
      for (int j = 0; j < 8; j++) vv[j] = vr[(p+j)*256];
#pragma unroll
      for (int j = 0; j < 8; j++) ss[j] = sc[r*48 + p + j];
      __builtin_amdgcn_sched_barrier(0);
#pragma unroll
      for (int j = 0; j < 8; j++) a += ss[j] * vv[j];
    }
    for (; p < nk; p++) a += sc[r*48 + p] * vr[p*256];
    ao[r*32 + d2] = a;
  }
  __syncthreads();
}

// ================= the single persistent kernel =================
__global__ void __launch_bounds__(512, 2)
genrev12_kernel(GParams P) {
  __shared__ float sm[8448];
  float* ws = P.ws;
  const int wg = blockIdx.x;
  const int t  = threadIdx.x;

  // ---- E0: encoder embeddings + pe ----
  if (t < 256) {
    for (int rr = 0; rr < 12; rr++) {
      int row = wg*12 + rr;
      int b = row / 48, s = row % 48;
      int tok = (s < 32) ? P.xc[b*32 + s] : P.xct[b*16 + (s - 32)];
      ws[X_OFF + row*256 + t] = P.emb[(s*1024 + tok)*256 + t] + pe_val(s, t);
    }
  }
  gbar(&g_cntA, &g_genA, 256);

  // ---- encoder: 6 post-norm layers ----
  float* Xp = ws + X_OFF;
  for (int l = 0; l < 6; l++) {
    gemm_stage(Xp, P.ewqkv + l*768*256, P.ebqkv + l*768, nullptr, ws + QKV_OFF, 3072, 768, 256, 0, sm);
    gbar(&g_cntA, &g_genA, 256);
    enc_attn_stage(ws + QKV_OFF, ws + AO_OFF, sm);
    gbar(&g_cntA, &g_genA, 256);
    gemm_stage(ws + AO_OFF, P.ewo + l*256*256, P.ebo + l*256, Xp, ws + RES1_OFF, 3072, 256, 256, 0, sm);
    gbar(&g_cntA, &g_genA, 256);
    ln_stage(ws + RES1_OFF, P.elnw + (l*2 + 0)*256, P.elnb + (l*2 + 0)*256, ws + X1_OFF, 3072);
    gbar(&g_cntA, &g_genA, 256);
    gemm_stage(ws + X1_OFF, P.ew1 + l*1024*256, P.eb1 + l*1024, nullptr, ws + HB_OFF, 3072, 1024, 256, 1, sm);
    gbar(&g_cntA, &g_genA, 256);
    gemm_stage(ws + HB_OFF, P.ew2 + l*256*1024, P.eb2 + l*256, ws + X1_OFF, ws + RES2_OFF, 3072, 256, 1024, 0, sm);
    gbar(&g_cntA, &g_genA, 256);
    ln_stage(ws + RES2_OFF, P.elnw + (l*2 + 1)*256, P.elnb + (l*2 + 1)*256, Xp, 3072);
    gbar(&g_cntA, &g_genA, 256);
  }
  ln_stage(Xp, P.lnfw, P.lnfb, ws + MEM_OFF, 3072);
  gbar(&g_cntA, &g_genA, 256);
  // cross K (plain, temp at PCK) and cross V (final layout) for all 6 layers
  for (int l = 0; l < 6; l++) {
    gemm_stage(ws + MEM_OFF, P.cwqkv + (l*768 + 256)*256, P.cbqkv + l*768 + 256, nullptr,
               ws + PCK_OFF + l*786432, 3072, 256, 256, 0, sm);
    gemm_stage(ws + MEM_OFF, P.cwqkv + (l*768 + 512)*256, P.cbqkv + l*768 + 512, nullptr,
               ws + CV_OFF + l*786432, 3072, 256, 256, 0, sm);
  }
  gbar(&g_cntA, &g_genA, 256);

  // ---- transpose phase: decode weights -> [k][o]; plain cross-K -> [d4][p][4] ----
  {
    const int gt = wg*512 + t;
    const int GT = 256*512;
    for (int idx = gt; idx < 6*256*768; idx += GT) {
      int l = idx / 196608, r = idx - l*196608;
      int k = r / 768, o = r - k*768;
      ws[SWQKVT + idx] = P.swqkv[(l*768 + o)*256 + k];
    }
    for (int idx = gt; idx < 6*65536; idx += GT) {
      int l = idx >> 16, r = idx & 65535, k = r >> 8, o = r & 255;
      ws[SWOT + idx] = P.swo[(l*256 + o)*256 + k];
    }
    for (int idx = gt; idx < 6*65536; idx += GT) {
      int l = idx >> 16, r = idx & 65535, k = r >> 8, o = r & 255;
      ws[CWQT + idx] = P.cwqkv[(l*768 + o)*256 + k];
    }
    for (int idx = gt; idx < 6*65536; idx += GT) {
      int l = idx >> 16, r = idx & 65535, k = r >> 8, o = r & 255;
      ws[CWOT + idx] = P.cwo[(l*256 + o)*256 + k];
    }
    for (int idx = gt; idx < 6*262144; idx += GT) {
      int l = idx >> 18, r = idx & 262143, k = r >> 10, o = r & 1023;
      ws[DW1T + idx] = P.dw1[(l*1024 + o)*256 + k];
    }
    for (int idx = gt; idx < 6*262144; idx += GT) {
      int l = idx >> 18, r = idx & 262143, k = r >> 8, o = r & 255;
      ws[DW2T + idx] = P.dw2[(l*256 + o)*1024 + k];
    }
    // CKT[l][b][d4][p][c] from plain CK[l][b*48+p][d]
    for (int idx = gt; idx < 6*64*48*256; idx += GT) {
      int l = idx / 786432, r = idx - l*786432;
      int b = r / 12288, q = r - b*12288;
      int d4 = q / 192, s2 = q - d4*192;
      int p = s2 >> 2, c = s2 & 3;
      ws[CKT_OFF + idx] = ws[PCK_OFF + l*786432 + (b*48 + p)*256 + d4*4 + c];
    }
    // zero the cohort soft-sync slots (relaxed atomic stores -> LLC)
    unsigned* ssync = (unsigned*)(ws + SSYNC_OFF);
    for (int idx = gt; idx < 3072; idx += GT)
      __hip_atomic_store(&ssync[idx], 0u, __ATOMIC_RELAXED, __HIP_MEMORY_SCOPE_AGENT);
  }
  gbar(&g_cntA, &g_genA, 256);

  // ================= barrier-free per-row decode: WG b owns batch row b =================
  if (wg >= 64) return;
  const int b = wg;
  const int grp = wg & 7;      // round-robin dispatch: same grp -> same XCD-L2
  unsigned* ssync = (unsigned*)(ws + SSYNC_OFF);

  float* cur  = sm;           // 256
  float* qv   = sm + 256;     // 256
  float* av   = sm + 512;     // 256
  float* y1   = sm + 768;     // 256
  float* y2   = sm + 1024;    // 256
  float* hbf  = sm + 1280;    // 1024
  float* sc   = sm + 2304;    // 384
  float* red  = sm + 2688;    // 32
  float* y0   = sm + 2720;    // 256
  float* bvv  = sm + 2976;    // 256
  int*   bii  = (int*)(sm + 3232); // 256
  float* part = sm + 3488;    // 2048

  if (t < 256) y0[t] = P.sos[t] + pe_val(0, t);
  __syncthreads();

  for (int i = 0; i < 48; i++) {
    if (t < 256) cur[t] = y0[t];
    __syncthreads();
    for (int l = 0; l < 6; l++) {
      // keep the 8 same-XCD WGs inside the same layer window (weight L2 sharing)
      cohort_sync(ssync + (i*7 + l)*8 + grp);
      const int skt = SKT_OFF + l*786432 + b*12288;
      const int sv  = SV_OFF  + l*786432 + b*12288;
      const int ckt = CKT_OFF + l*786432 + b*12288;
      const int cv  = CV_OFF  + l*786432 + b*12288;
      // --- self QKV (transposed, coalesced, 2-way k-split) ---
      matvec_t<768,2,256>(ws + SWQKVT + l*196608, cur, part);
      for (int o = t; o < 768; o += 512) {
        float v = part[o] + part[768 + o] + P.sbqkv[l*768 + o];
        if (o < 256)      qv[o] = v;
        else if (o < 512) { int d = o - 256; ws[skt + (d>>2)*192 + i*4 + (d&3)] = v; }
        else              ws[sv + i*256 + (o - 512)] = v;
      }
      __syncthreads();
      attn_dec(qv, ws + skt, ws + sv, i + 1, sc, red, av);
      // --- self out-proj + residual + LN ---
      matvec_t<256,8,256>(ws + SWOT + l*65536, av, part);
      if (t < 256) {
        float s = part[t];
#pragma unroll
        for (int kc = 1; kc < 8; kc++) s += part[kc*256 + t];
        y1[t] = cur[t] + (s + P.sbo[l*256 + t]);
      }
      __syncthreads();
      if (t < 64) wave_ln_row(y1, P.dlnw + (l*3 + 0)*256, P.dlnb + (l*3 + 0)*256);
      __syncthreads();
      // --- cross q ---
      matvec_t<256,8,256>(ws + CWQT + l*65536, y1, part);
      if (t < 256) {
        float s = part[t];
#pragma unroll
        for (int kc = 1; kc < 8; kc++) s += part[kc*256 + t];
        qv[t] = s + P.cbqkv[l*768 + t];
      }
      __syncthreads();
      attn_dec(qv, ws + ckt, ws + cv, 48, sc, red, av);
      matvec_t<256,8,256>(ws + CWOT + l*65536, av, part);
      if (t < 256) {
        float s = part[t];
#pragma unroll
        for (int kc = 1; kc < 8; kc++) s += part[kc*256 + t];
        y2[t] = y1[t] + (s + P.cbo[l*256 + t]);
      }
      __syncthreads();
      if (t < 64) wave_ln_row(y2, P.dlnw + (l*3 + 1)*256, P.dlnb + (l*3 + 1)*256);
      __syncthreads();
      // --- FFN ---
      matvec_t<1024,2,256>(ws + DW1T + l*262144, y2, part);
      for (int o = t; o < 1024; o += 512)
        hbf[o] = fmaxf(part[o] + part[1024 + o] + P.db1[l*1024 + o], 0.0f);
      __syncthreads();
      matvec_t<256,8,1024>(ws + DW2T + l*262144, hbf, part);
      if (t < 256) {
        float s = part[t];
#pragma unroll
        for (int kc = 1; kc < 8; kc++) s += part[kc*256 + t];
        cur[t] = y2[t] + (s + P.db2[l*256 + t]);
      }
      __syncthreads();
      if (t < 64) wave_ln_row(cur, P.dlnw + (l*3 + 2)*256, P.dlnb + (l*3 + 2)*256);
      __syncthreads();
    }
    // --- final LN (lnf[1]) ---
    if (t < 64) wave_ln_row(cur, P.lnfw + 256, P.lnfb + 256);
    __syncthreads();
    // --- head: wave-cooperative rows; 2-deep C++ pipelined blocks (A/B) so the
    //     next 8 hw-row loads can fly during the current shfl-reduce chains ---
    cohort_sync(ssync + (i*7 + 6)*8 + grp);
    {
      const int wv = t >> 6, lane = t & 63;
      const float4 x4 = *(const float4*)(cur + lane*4);
      float4 wlA[8], wlB[8];
#pragma unroll
      for (int u = 0; u < 4; u++) {
        int o = u*16 + wv;
        wlA[u*2]   = *(const float4*)(P.hw + (size_t)(i*1024 + o)*256 + lane*4);
        wlA[u*2+1] = *(const float4*)(P.hw + (size_t)(i*1024 + o + 8)*256 + lane*4);
      }
      for (int base = 0; base < 1024; base += 128) {
#pragma unroll
        for (int u = 0; u < 4; u++) {
          int o = base + 64 + u*16 + wv;
          wlB[u*2]   = *(const float4*)(P.hw + (size_t)(i*1024 + o)*256 + lane*4);
          wlB[u*2+1] = *(const float4*)(P.hw + (size_t)(i*1024 + o + 8)*256 + lane*4);
        }
        __builtin_amdgcn_sched_barrier(0);
#pragma unroll
        for (int u = 0; u < 4; u++) {
          int o = base + u*16 + wv, o2 = o + 8;
          float4 wa = wlA[u*2], wb = wlA[u*2+1];
          float sa = wa.x*x4.x; sa += wa.y*x4.y; sa += wa.z*x4.z; sa += wa.w*x4.w;
          float sb = wb.x*x4.x; sb += wb.y*x4.y; sb += wb.z*x4.z; sb += wb.w*x4.w;
#pragma unroll
          for (int m = 1; m < 64; m <<= 1) { sa += __shfl_xor(sa, m); sb += __shfl_xor(sb, m); }
          if (lane == 0) {
            hbf[o]  = sa + P.hb[i*1024 + o];
            hbf[o2] = sb + P.hb[i*1024 + o2];
          }
        }
        if (base + 128 < 1024) {
#pragma unroll
          for (int u = 0; u < 4; u++) {
            int o = base + 128 + u*16 + wv;
            wlA[u*2]   = *(const float4*)(P.hw + (size_t)(i*1024 + o)*256 + lane*4);
            wlA[u*2+1] = *(const float4*)(P.hw + (size_t)(i*1024 + o + 8)*256 + lane*4);
          }
        }
        __builtin_amdgcn_sched_barrier(0);
#pragma unroll
        for (int u = 0; u < 4; u++) {
          int o = base + 64 + u*16 + wv, o2 = o + 8;
          float4 wa = wlB[u*2], wb = wlB[u*2+1];
          float sa = wa.x*x4.x; sa += wa.y*x4.y; sa += wa.z*x4.z; sa += wa.w*x4.w;
          float sb = wb.x*x4.x; sb += wb.y*x4.y; sb += wb.z*x4.z; sb += wb.w*x4.w;
#pragma unroll
          for (int m = 1; m < 64; m <<= 1) { sa += __shfl_xor(sa, m); sb += __shfl_xor(sb, m); }
          if (lane == 0) {
            hbf[o]  = sa + P.hb[i*1024 + o];
            hbf[o2] = sb + P.hb[i*1024 + o2];
          }
        }
      }
    }
    __syncthreads();
    for (int o = t; o < 1024; o += 512)
      P.out[3072 + i*65536 + b*1024 + o] = hbf[o];
    __syncthreads();
    // --- gumbel-argmax sampling: max-by-(value, smaller-index) is order-
    //     independent -> in-wave shfl reduce + 4-way merge (2 syncs, not 9) ---
    unsigned k0, k1;
    step_key(i, k0, k1);
    if (t < 256) {
      float bestv = -INFINITY; int besti = 0;
#pragma unroll
      for (int e = 0; e < 4; e++) {
        int v = t*4 + e;
        unsigned bits = gumbel_bits(k0, k1, b, v);
        float f = __uint_as_float((bits >> 9) | 0x3f800000u);
        float u = fmaxf(f - 1.0f, 1.17549435e-38f);
        float g = -logf(-logf(u));
        float z = g + hbf[v] / 0.1f;
        if (z > bestv) { bestv = z; besti = v; }
      }
#pragma unroll
      for (int mm = 1; mm < 64; mm <<= 1) {
        float ov = __shfl_xor(bestv, mm);
        int   oi = __shfl_xor(besti, mm);
        if (ov > bestv || (ov == bestv && oi < besti)) { bestv = ov; besti = oi; }
      }
      if ((t & 63) == 0) { bvv[t >> 6] = bestv; bii[t >> 6] = besti; }
    }
    __syncthreads();
    if (t == 0) {
      float bv = bvv[0]; int bi = bii[0];
#pragma unroll
      for (int w = 1; w < 4; w++) {
        float ov = bvv[w]; int oi = bii[w];
        if (ov > bv || (ov == bv && oi < bi)) { bv = ov; bi = oi; }
      }
      bii[0] = bi;
    }
    __syncthreads();
    const int ch = bii[0];
    if (t == 0) {
      if (i < 32) P.out[b*32 + i] = (float)ch;
      else        P.out[2048 + b*16 + (i - 32)] = (float)ch;
    }
    if (t < 256) y0[t] = P.emb[(i*1024 + ch)*256 + t] + pe_val(i + 1, t);
    __syncthreads();
  }
}

extern "C" void kernel_launch(void* const* d_in, const int* in_sizes, int n_in,
                              void* d_out, int out_size, void* d_ws, size_t ws_size,
                              hipStream_t stream) {
  (void)in_sizes; (void)n_in; (void)out_size; (void)ws_size;
  GParams p;
  p.xc    = (const int*)  d_in[0];
  p.xct   = (const int*)  d_in[1];
  p.sos   = (const float*)d_in[2];
  p.emb   = (const float*)d_in[3];
  p.hw    = (const float*)d_in[4];
  p.hb    = (const float*)d_in[5];
  p.ewqkv = (const float*)d_in[6];
  p.ebqkv = (const float*)d_in[7];
  p.ewo   = (const float*)d_in[8];
  p.ebo   = (const float*)d_in[9];
  p.ew1   = (const float*)d_in[10];
  p.eb1   = (const float*)d_in[11];
  p.ew2   = (const float*)d_in[12];
  p.eb2   = (const float*)d_in[13];
  p.elnw  = (const float*)d_in[14];
  p.elnb  = (const float*)d_in[15];
  p.swqkv = (const float*)d_in[16];
  p.sbqkv = (const float*)d_in[17];
  p.swo   = (const float*)d_in[18];
  p.sbo   = (const float*)d_in[19];
  p.cwqkv = (const float*)d_in[20];
  p.cbqkv = (const float*)d_in[21];
  p.cwo   = (const float*)d_in[22];
  p.cbo   = (const float*)d_in[23];
  p.dw1   = (const float*)d_in[24];
  p.db1   = (const float*)d_in[25];
  p.dw2   = (const float*)d_in[26];
  p.db2   = (const float*)d_in[27];
  p.dlnw  = (const float*)d_in[28];
  p.dlnb  = (const float*)d_in[29];
  p.lnfw  = (const float*)d_in[30];
  p.lnfb  = (const float*)d_in[31];
  p.out   = (float*)d_out;
  p.ws    = (float*)d_ws;
  hipLaunchKernelGGL(genrev12_kernel, dim3(256), dim3(512), 0, stream, p);
}